// Round 4
// baseline (2545.901 us; speedup 1.0000x reference)
//
#include <hip/hip_runtime.h>
#include <math.h>

#define T_STEPS 12
#define N_NODES 10000
#define MP 10112  // 79*128, padded M
#define D_IN 256
#define H_DIM 512
#define H3 1536
#define E_EDGES 160000
#define NUM_CONVS 2

typedef __bf16 bf16x8 __attribute__((ext_vector_type(8)));
typedef float floatx4 __attribute__((ext_vector_type(4)));
typedef _Float16 f16x4 __attribute__((ext_vector_type(4)));
typedef unsigned short u16;
typedef unsigned int u32;

__device__ __forceinline__ u16 f2bf(float f) {
  unsigned int u = __float_as_uint(f);
  u += 0x7FFFu + ((u >> 16) & 1u);  // round-nearest-even (no NaN inputs)
  return (u16)(u >> 16);
}
__device__ __forceinline__ float bf2f(u16 s) {
  return __uint_as_float(((unsigned int)s) << 16);
}
__device__ __forceinline__ float sigmoid_f(float x) {
  return __builtin_amdgcn_rcpf(1.0f + __expf(-x));
}
__device__ __forceinline__ float tanh_f(float x) {
  return 1.0f - 2.0f * __builtin_amdgcn_rcpf(1.0f + __expf(2.0f * x));
}

__device__ __forceinline__ void glds16(const void* g, void* l) {
  __builtin_amdgcn_global_load_lds(
      (const __attribute__((address_space(1))) unsigned int*)g,
      (__attribute__((address_space(3))) unsigned int*)l, 16, 0, 0);
}

#define MFMA16(a, b, c) __builtin_amdgcn_mfma_f32_16x16x32_bf16((a), (b), (c), 0, 0, 0)

// One gru K-step (BK=32): 3 sub-phases (hi*hi, hi*lo, lo*hi), each a
// barrier-pair around a 12-MFMA cluster with setprio. G2 = gate index for
// the 3rd column group (2 in phase-1 / 3 in phase-2) -- compile-time so the
// accumulator is statically indexed (rule #20).
template <int G2>
__device__ __forceinline__ void gru_kstep(const u16 (&As)[2][2][4096],
                                          const u16 (&Bs)[2][2][3072], int cur,
                                          int aoff, int boff,
                                          floatx4 (&acc)[4][4]) {
  bf16x8 ah[4], bh[3], bl[3], al[4];
#pragma unroll
  for (int i = 0; i < 4; ++i) ah[i] = *(const bf16x8*)&As[cur][0][aoff + i * 512];
#pragma unroll
  for (int g = 0; g < 3; ++g) bh[g] = *(const bf16x8*)&Bs[cur][0][boff + g * 512];
  __builtin_amdgcn_s_setprio(1);
#pragma unroll
  for (int i = 0; i < 4; ++i) {
    acc[i][0] = MFMA16(ah[i], bh[0], acc[i][0]);
    acc[i][1] = MFMA16(ah[i], bh[1], acc[i][1]);
    acc[i][G2] = MFMA16(ah[i], bh[2], acc[i][G2]);
  }
  __builtin_amdgcn_s_setprio(0);
  __builtin_amdgcn_s_barrier();
#pragma unroll
  for (int g = 0; g < 3; ++g) bl[g] = *(const bf16x8*)&Bs[cur][1][boff + g * 512];
  __builtin_amdgcn_s_setprio(1);
#pragma unroll
  for (int i = 0; i < 4; ++i) {
    acc[i][0] = MFMA16(ah[i], bl[0], acc[i][0]);
    acc[i][1] = MFMA16(ah[i], bl[1], acc[i][1]);
    acc[i][G2] = MFMA16(ah[i], bl[2], acc[i][G2]);
  }
  __builtin_amdgcn_s_setprio(0);
  __builtin_amdgcn_s_barrier();
#pragma unroll
  for (int i = 0; i < 4; ++i) al[i] = *(const bf16x8*)&As[cur][1][aoff + i * 512];
  __builtin_amdgcn_s_setprio(1);
#pragma unroll
  for (int i = 0; i < 4; ++i) {
    acc[i][0] = MFMA16(al[i], bh[0], acc[i][0]);
    acc[i][1] = MFMA16(al[i], bh[1], acc[i][1]);
    acc[i][G2] = MFMA16(al[i], bh[2], acc[i][G2]);
  }
  __builtin_amdgcn_s_setprio(0);
  __builtin_amdgcn_s_barrier();
}

// ============ fused GRU: pipelined two-phase bf16x3 GEMM + in-reg gate ======
// 2-deep staging pipeline (dbuf, counted vmcnt never 0 mid-loop), 3 sub-phase
// K-step, single 24-tile pipeline spanning both GEMM phases, XCD swizzle.
__global__ __launch_bounds__(256) void gru_fused(
    const u16* __restrict__ Xhi, const u16* __restrict__ Xlo,      // (MP,256)
    const u16* __restrict__ Shi_in, const u16* __restrict__ Slo_in,// (MP,512)
    const u16* __restrict__ Bxh, const u16* __restrict__ Bxl,      // WihG (1536,256)
    const u16* __restrict__ Bhh, const u16* __restrict__ Bhl,      // WhhG (1536,512)
    const float* __restrict__ bihg, const float* __restrict__ bhhg,
    u16* __restrict__ Ghi, u16* __restrict__ Glo) {
  __shared__ u16 As[2][2][4096];  // [buf][hi/lo] 128 rows x 32 k, swizzled
  __shared__ u16 Bs[2][2][3072];  // [buf][hi/lo] 96 rows x 32 k
  const int tid = threadIdx.x;
  const int lane = tid & 63;
  const int wave = tid >> 6;
  // T1: XCD-chunked swizzle; 1264 blocks = 8 * 158 (exactly divisible)
  const int bid = blockIdx.y * 16 + blockIdx.x;
  const int lid = (bid & 7) * 158 + (bid >> 3);
  const int bx = lid & 15, by = lid >> 4;
  const int rbase = by * 128;
  const int cbase = bx * 96;

  // slot decompositions (K-independent)
  const int sa1 = tid, sa2 = tid + 256;
  const int ra1 = sa1 >> 2, ca1 = (sa1 & 3) ^ ((ra1 >> 1) & 3);
  const int ra2 = sa2 >> 2, ca2 = (sa2 & 3) ^ ((ra2 >> 1) & 3);
  const int la1 = (sa1 >> 6) << 9;
  const int la2 = (sa2 >> 6) << 9;
  const int sb1 = tid;
  const int rb1 = sb1 >> 2, cb1 = (sb1 & 3) ^ ((rb1 >> 1) & 3);
  const int lb1 = (sb1 >> 6) << 9;
  const int sb2 = 256 + tid;
  const int rb2 = sb2 >> 2, cb2 = (sb2 & 3) ^ ((rb2 >> 1) & 3);
  const int lb2 = (sb2 >> 6) << 9;

  const int wr = (wave >> 1) * 64;
  const int wc = (wave & 1) * 48;
  const int lrow = lane & 15;
  const int kq = lane >> 4;
  const int swz = kq ^ ((lrow >> 1) & 3);
  const int aoff = (wr + lrow) * 32 + swz * 8;
  const int boff = (wc + lrow) * 32 + swz * 8;

  // global byte-element offsets for both phases
  const size_t xA1 = (size_t)(rbase + ra1) * 256 + ca1 * 8;
  const size_t xA2 = (size_t)(rbase + ra2) * 256 + ca2 * 8;
  const size_t hA1 = (size_t)(rbase + ra1) * 512 + ca1 * 8;
  const size_t hA2 = (size_t)(rbase + ra2) * 512 + ca2 * 8;
  const size_t xB1 = (size_t)(cbase + rb1) * 256 + cb1 * 8;
  const size_t xB2 = (size_t)(cbase + rb2) * 256 + cb2 * 8;
  const size_t hB1 = (size_t)(cbase + rb1) * 512 + cb1 * 8;
  const size_t hB2 = (size_t)(cbase + rb2) * 512 + cb2 * 8;

  // stage tile t (t<8: phase-1 X/Wih, t>=8: phase-2 S/Whh) into buffer `buf`.
  // Per-wave load count: waves 0-1 -> 8, waves 2-3 -> 6 (wave-uniform).
  auto stage = [&](int buf, int t) {
    if (t < 8) {
      const int kt = t * 32;
      glds16(Xhi + xA1 + kt, &As[buf][0][la1]);
      glds16(Xhi + xA2 + kt, &As[buf][0][la2]);
      glds16(Xlo + xA1 + kt, &As[buf][1][la1]);
      glds16(Xlo + xA2 + kt, &As[buf][1][la2]);
      glds16(Bxh + xB1 + kt, &Bs[buf][0][lb1]);
      glds16(Bxl + xB1 + kt, &Bs[buf][1][lb1]);
      if (tid < 128) {
        glds16(Bxh + xB2 + kt, &Bs[buf][0][lb2]);
        glds16(Bxl + xB2 + kt, &Bs[buf][1][lb2]);
      }
    } else {
      const int kt = (t - 8) * 32;
      glds16(Shi_in + hA1 + kt, &As[buf][0][la1]);
      glds16(Shi_in + hA2 + kt, &As[buf][0][la2]);
      glds16(Slo_in + hA1 + kt, &As[buf][1][la1]);
      glds16(Slo_in + hA2 + kt, &As[buf][1][la2]);
      glds16(Bhh + hB1 + kt, &Bs[buf][0][lb1]);
      glds16(Bhl + hB1 + kt, &Bs[buf][1][lb1]);
      if (tid < 128) {
        glds16(Bhh + hB2 + kt, &Bs[buf][0][lb2]);
        glds16(Bhl + hB2 + kt, &Bs[buf][1][lb2]);
      }
    }
  };

  floatx4 acc[4][4];  // [row-frag][gate: 0=r 1=z 2=ni 3=nh]
#pragma unroll
  for (int i = 0; i < 4; ++i)
#pragma unroll
    for (int g = 0; g < 4; ++g) acc[i][g] = (floatx4){0.f, 0.f, 0.f, 0.f};

  // ---- pipelined 24-tile K-loop (8 phase-1 + 16 phase-2, no mid drain) ----
  stage(0, 0);
  stage(1, 1);
  int cur = 0;
  for (int t = 0; t < 8; ++t) {
    // wait own tile-t loads (leave tile t+1's in flight), then sync
    if (wave < 2) asm volatile("s_waitcnt vmcnt(8)" ::: "memory");
    else          asm volatile("s_waitcnt vmcnt(6)" ::: "memory");
    __builtin_amdgcn_s_barrier();
    __builtin_amdgcn_sched_barrier(0);
    gru_kstep<2>(As, Bs, cur, aoff, boff, acc);
    __builtin_amdgcn_sched_barrier(0);
    stage(cur, t + 2);  // safe: closing barrier above, reads retired
    cur ^= 1;
  }
  for (int t = 8; t < 24; ++t) {
    if (t < 23) {
      if (wave < 2) asm volatile("s_waitcnt vmcnt(8)" ::: "memory");
      else          asm volatile("s_waitcnt vmcnt(6)" ::: "memory");
    } else {
      asm volatile("s_waitcnt vmcnt(0)" ::: "memory");
    }
    __builtin_amdgcn_s_barrier();
    __builtin_amdgcn_sched_barrier(0);
    gru_kstep<3>(As, Bs, cur, aoff, boff, acc);
    __builtin_amdgcn_sched_barrier(0);
    if (t + 2 < 24) stage(cur, t + 2);
    cur ^= 1;
  }

  // ---------------- epilogue: GRU gate in registers ----------------
  const int c0g = cbase + wc + lrow;
  const int j = (((bx << 1) | (wave & 1)) << 4) | lrow;
  const float brz0 = bihg[c0g] + bhhg[c0g];
  const float brz1 = bihg[c0g + 16] + bhhg[c0g + 16];
  const float bin = bihg[c0g + 32];
  const float bhn = bhhg[c0g + 32];
#pragma unroll
  for (int i = 0; i < 4; ++i) {
    int r0 = rbase + wr + i * 16 + kq * 4;
#pragma unroll
    for (int rr = 0; rr < 4; ++rr) {
      int row = r0 + rr;
      if (row >= N_NODES) continue;
      float r = sigmoid_f(acc[i][0][rr] + brz0);
      float z = sigmoid_f(acc[i][1][rr] + brz1);
      float nn = tanh_f(acc[i][2][rr] + bin + r * (acc[i][3][rr] + bhn));
      size_t o = (size_t)row * H_DIM + j;
      float hp = bf2f(Shi_in[o]) + bf2f(Slo_in[o]);
      float hv = (1.0f - z) * nn + z * hp;
      u16 hb = f2bf(hv);
      Ghi[o] = hb;
      Glo[o] = f2bf(hv - bf2f(hb));
    }
  }
}

// One conv K-step: 3 sub-phases of 8 MFMA each.
__device__ __forceinline__ void conv_kstep(const u16 (&As)[2][2][2048],
                                           const u16 (&Bs)[2][2][4096], int cur,
                                           int aoff, int boff,
                                           floatx4 (&acc)[2][4]) {
  bf16x8 ah[2], bh[4], bl[4], al[2];
#pragma unroll
  for (int i = 0; i < 2; ++i) ah[i] = *(const bf16x8*)&As[cur][0][aoff + i * 512];
#pragma unroll
  for (int jj = 0; jj < 4; ++jj) bh[jj] = *(const bf16x8*)&Bs[cur][0][boff + jj * 512];
  __builtin_amdgcn_s_setprio(1);
#pragma unroll
  for (int i = 0; i < 2; ++i)
#pragma unroll
    for (int jj = 0; jj < 4; ++jj) acc[i][jj] = MFMA16(ah[i], bh[jj], acc[i][jj]);
  __builtin_amdgcn_s_setprio(0);
  __builtin_amdgcn_s_barrier();
#pragma unroll
  for (int jj = 0; jj < 4; ++jj) bl[jj] = *(const bf16x8*)&Bs[cur][1][boff + jj * 512];
  __builtin_amdgcn_s_setprio(1);
#pragma unroll
  for (int i = 0; i < 2; ++i)
#pragma unroll
    for (int jj = 0; jj < 4; ++jj) acc[i][jj] = MFMA16(ah[i], bl[jj], acc[i][jj]);
  __builtin_amdgcn_s_setprio(0);
  __builtin_amdgcn_s_barrier();
#pragma unroll
  for (int i = 0; i < 2; ++i) al[i] = *(const bf16x8*)&As[cur][1][aoff + i * 512];
  __builtin_amdgcn_s_setprio(1);
#pragma unroll
  for (int i = 0; i < 2; ++i)
#pragma unroll
    for (int jj = 0; jj < 4; ++jj) acc[i][jj] = MFMA16(al[i], bh[jj], acc[i][jj]);
  __builtin_amdgcn_s_setprio(0);
  __builtin_amdgcn_s_barrier();
}

// ============ conv GEMM: 64x128 bf16x3, pipelined, fp16 output ==============
__global__ __launch_bounds__(256) void gemm_conv(
    const u16* __restrict__ Ahi, const u16* __restrict__ Alo,
    const u16* __restrict__ Bhi, const u16* __restrict__ Blo,
    _Float16* __restrict__ C, int M, int Nn, int K) {
  __shared__ u16 As[2][2][2048];  // [buf][hi/lo] 64 rows x 32 k
  __shared__ u16 Bs[2][2][4096];  // [buf][hi/lo] 128 rows x 32 k
  const int tid = threadIdx.x;
  const int lane = tid & 63;
  const int wave = tid >> 6;
  // T1: XCD-chunked swizzle; 632 blocks = 8 * 79
  const int bid = blockIdx.y * 4 + blockIdx.x;
  const int lid = (bid & 7) * 79 + (bid >> 3);
  const int bx = lid & 3, by = lid >> 2;
  const int rbase = by * 64;
  const int cbase = bx * 128;

  const int sa = tid;
  const int ra = sa >> 2, ca = (sa & 3) ^ ((ra >> 1) & 3);
  const int la = (sa >> 6) << 9;
  const int sb1 = tid, sb2 = tid + 256;
  const int rb1 = sb1 >> 2, cb1 = (sb1 & 3) ^ ((rb1 >> 1) & 3);
  const int rb2 = sb2 >> 2, cb2 = (sb2 & 3) ^ ((rb2 >> 1) & 3);
  const int lb1 = (sb1 >> 6) << 9, lb2 = (sb2 >> 6) << 9;
  const size_t oA = (size_t)(rbase + ra) * K + ca * 8;
  const size_t oB1 = (size_t)(cbase + rb1) * K + cb1 * 8;
  const size_t oB2 = (size_t)(cbase + rb2) * K + cb2 * 8;

  const int wr = (wave >> 1) * 32;
  const int wc = (wave & 1) * 64;
  const int lrow = lane & 15;
  const int kq = lane >> 4;
  const int swz = kq ^ ((lrow >> 1) & 3);
  const int aoff = (wr + lrow) * 32 + swz * 8;
  const int boff = (wc + lrow) * 32 + swz * 8;

  auto stage = [&](int buf, int t) {  // 6 loads per thread, uniform
    const int kt = t * 32;
    glds16(Ahi + oA + kt, &As[buf][0][la]);
    glds16(Alo + oA + kt, &As[buf][1][la]);
    glds16(Bhi + oB1 + kt, &Bs[buf][0][lb1]);
    glds16(Bhi + oB2 + kt, &Bs[buf][0][lb2]);
    glds16(Blo + oB1 + kt, &Bs[buf][1][lb1]);
    glds16(Blo + oB2 + kt, &Bs[buf][1][lb2]);
  };

  floatx4 acc[2][4];
#pragma unroll
  for (int i = 0; i < 2; ++i)
#pragma unroll
    for (int jj = 0; jj < 4; ++jj) acc[i][jj] = (floatx4){0.f, 0.f, 0.f, 0.f};

  const int NT = K >> 5;  // 16
  stage(0, 0);
  stage(1, 1);
  int cur = 0;
  for (int t = 0; t < NT; ++t) {
    if (t < NT - 1) asm volatile("s_waitcnt vmcnt(6)" ::: "memory");
    else            asm volatile("s_waitcnt vmcnt(0)" ::: "memory");
    __builtin_amdgcn_s_barrier();
    __builtin_amdgcn_sched_barrier(0);
    conv_kstep(As, Bs, cur, aoff, boff, acc);
    __builtin_amdgcn_sched_barrier(0);
    if (t + 2 < NT) stage(cur, t + 2);
    cur ^= 1;
  }

#pragma unroll
  for (int jj = 0; jj < 4; ++jj) {
    int col = cbase + wc + jj * 16 + lrow;
#pragma unroll
    for (int i = 0; i < 2; ++i) {
      int r0 = rbase + wr + i * 16 + kq * 4;
#pragma unroll
      for (int rr = 0; rr < 4; ++rr) {
        int row = r0 + rr;
        if (row < M) C[(size_t)row * Nn + col] = (_Float16)acc[i][jj][rr];
      }
    }
  }
}

// ---------------- split / preprocessing kernels ----------------
__global__ void split_grouped(const float* __restrict__ W, u16* __restrict__ hi,
                              u16* __restrict__ lo, int K) {
  int i = blockIdx.x * 256 + threadIdx.x;
  if (i >= H3 * K) return;
  int r3h = i / K, k = i - r3h * K;
  int g = r3h >> 9, j = r3h & 511;
  int nr = ((j >> 4) * 48) + (g << 4) + (j & 15);
  float v = W[i];
  u16 h = f2bf(v);
  size_t o = (size_t)nr * K + k;
  hi[o] = h;
  lo[o] = f2bf(v - bf2f(h));
}

__global__ void bias_grouped(const float* __restrict__ bih, const float* __restrict__ bhh,
                             float* __restrict__ bihg, float* __restrict__ bhhg) {
  int n = blockIdx.x * 256 + threadIdx.x;
  if (n >= H3) return;
  int g = n >> 9, j = n & 511;
  int nr = ((j >> 4) * 48) + (g << 4) + (j & 15);
  bihg[nr] = bih[n];
  bhhg[nr] = bhh[n];
}

__global__ void split_convw(const float* __restrict__ W, u16* __restrict__ hi,
                            u16* __restrict__ lo) {
  int o = blockIdx.x * 256 + threadIdx.x;
  if (o >= NUM_CONVS * H_DIM * H_DIM) return;
  int k = o & 511, j = (o >> 9) & 511, l = o >> 18;
  float v = W[(size_t)l * H_DIM * H_DIM + (size_t)k * H_DIM + j];
  u16 h = f2bf(v);
  hi[o] = h;
  lo[o] = f2bf(v - bf2f(h));
}

__global__ void split_xs(const float* __restrict__ xs, u16* __restrict__ hi,
                         u16* __restrict__ lo) {
  const int QP = MP * D_IN / 4;
  int q = blockIdx.x * 256 + threadIdx.x;
  if (q >= T_STEPS * QP) return;
  int t = q / QP;
  int rem = (q - t * QP) * 4;
  size_t o = (size_t)t * MP * D_IN + rem;
  uint2 hp = make_uint2(0u, 0u), lp = make_uint2(0u, 0u);
  if (rem < N_NODES * D_IN) {
    float4 v = *(const float4*)(xs + (size_t)t * N_NODES * D_IN + rem);
    float vv[4] = {v.x, v.y, v.z, v.w};
    u16 hb[4], lb[4];
#pragma unroll
    for (int k = 0; k < 4; ++k) {
      hb[k] = f2bf(vv[k]);
      lb[k] = f2bf(vv[k] - bf2f(hb[k]));
    }
    hp.x = (u32)hb[0] | ((u32)hb[1] << 16);
    hp.y = (u32)hb[2] | ((u32)hb[3] << 16);
    lp.x = (u32)lb[0] | ((u32)lb[1] << 16);
    lp.y = (u32)lb[2] | ((u32)lb[3] << 16);
  }
  *(uint2*)(hi + o) = hp;
  *(uint2*)(lo + o) = lp;
}

__global__ void deg_kernel(const int* __restrict__ col, const float* __restrict__ w,
                           float* __restrict__ deg, int* __restrict__ counts) {
  int e = blockIdx.x * blockDim.x + threadIdx.x;
  if (e >= E_EDGES) return;
  int c = col[e];
  atomicAdd(&deg[c], w[e]);
  atomicAdd(&counts[c], 1);
}

__global__ void dinv_kernel(float* __restrict__ deg_dinv, float* __restrict__ selfw) {
  int n = blockIdx.x * blockDim.x + threadIdx.x;
  if (n >= N_NODES) return;
  float d = deg_dinv[n] + 1.0f;
  float di = 1.0f / sqrtf(d);
  deg_dinv[n] = di;
  selfw[n] = 1.0f / d;
}

__global__ __launch_bounds__(1024) void scan_kernel(const int* __restrict__ counts,
                                                    int* __restrict__ offsets, int n) {
  __shared__ int smem[1024];
  __shared__ int carry_s;
  if (threadIdx.x == 0) carry_s = 0;
  __syncthreads();
  for (int base = 0; base < n; base += 1024) {
    int i = base + threadIdx.x;
    int v = (i < n) ? counts[i] : 0;
    smem[threadIdx.x] = v;
    __syncthreads();
    for (int off = 1; off < 1024; off <<= 1) {
      int t = (threadIdx.x >= off) ? smem[threadIdx.x - off] : 0;
      __syncthreads();
      smem[threadIdx.x] += t;
      __syncthreads();
    }
    if (i < n) offsets[i] = carry_s + smem[threadIdx.x] - v;
    int total = smem[1023];
    __syncthreads();
    if (threadIdx.x == 0) carry_s += total;
    __syncthreads();
  }
  if (threadIdx.x == 0) offsets[n] = carry_s;
}

__global__ void scatter_kernel(const int* __restrict__ row, const int* __restrict__ col,
                               const float* __restrict__ w, const float* __restrict__ dinv,
                               const int* __restrict__ offsets, int* __restrict__ cursor,
                               int* __restrict__ csr_row, float* __restrict__ csr_norm) {
  int e = blockIdx.x * blockDim.x + threadIdx.x;
  if (e >= E_EDGES) return;
  int r = row[e], c = col[e];
  float nrm = dinv[r] * w[e] * dinv[c];
  int pos = offsets[c] + atomicAdd(&cursor[c], 1);
  csr_row[pos] = r;
  csr_norm[pos] = nrm;
}

// ---------------- GCN aggregation (fp16 hW) + relu + split (+ final lin) ---
__device__ __forceinline__ void fma8h(double* a, float w, const _Float16* p) {
  f16x4 x = *(const f16x4*)p;
  f16x4 y = *(const f16x4*)(p + 256);
  double wd = (double)w;
  a[0] = fma(wd, (double)(float)x[0], a[0]);
  a[1] = fma(wd, (double)(float)x[1], a[1]);
  a[2] = fma(wd, (double)(float)x[2], a[2]);
  a[3] = fma(wd, (double)(float)x[3], a[3]);
  a[4] = fma(wd, (double)(float)y[0], a[4]);
  a[5] = fma(wd, (double)(float)y[1], a[5]);
  a[6] = fma(wd, (double)(float)y[2], a[6]);
  a[7] = fma(wd, (double)(float)y[3], a[7]);
}

template <bool FINAL>
__global__ __launch_bounds__(256) void agg_kernel(
    const _Float16* __restrict__ hW, const int* __restrict__ csr_row,
    const float* __restrict__ csr_norm, const int* __restrict__ offsets,
    const float* __restrict__ selfw, const float* __restrict__ bias,
    u16* __restrict__ Shi, u16* __restrict__ Slo,
    const float* __restrict__ lw, const float* __restrict__ lb,
    float* __restrict__ out) {
  const int n = (blockIdx.x << 2) | (threadIdx.x >> 6);
  const int lane = threadIdx.x & 63;
  if (n >= N_NODES) return;
  const int c0 = lane << 2;
  const int beg = offsets[n], end = offsets[n + 1];
  double a0[8] = {}, a1[8] = {};
  int j = beg;
  for (; j + 4 <= end; j += 4) {
    int r0 = csr_row[j], r1 = csr_row[j + 1], r2 = csr_row[j + 2], r3 = csr_row[j + 3];
    float w0 = csr_norm[j], w1 = csr_norm[j + 1], w2 = csr_norm[j + 2], w3 = csr_norm[j + 3];
    fma8h(a0, w0, hW + (size_t)r0 * H_DIM + c0);
    fma8h(a1, w1, hW + (size_t)r1 * H_DIM + c0);
    fma8h(a0, w2, hW + (size_t)r2 * H_DIM + c0);
    fma8h(a1, w3, hW + (size_t)r3 * H_DIM + c0);
  }
  for (; j < end; ++j) fma8h(a0, csr_norm[j], hW + (size_t)csr_row[j] * H_DIM + c0);

  const float sw = selfw[n];
  const _Float16* ps = hW + (size_t)n * H_DIM + c0;
  f16x4 sa = *(const f16x4*)ps;
  f16x4 sb = *(const f16x4*)(ps + 256);
  float4 ba = *(const float4*)(bias + c0);
  float4 bb = *(const float4*)(bias + 256 + c0);
  float v[8];
  v[0] = fmaxf(fmaf(sw, (float)sa[0], (float)(a0[0] + a1[0])) + ba.x, 0.f);
  v[1] = fmaxf(fmaf(sw, (float)sa[1], (float)(a0[1] + a1[1])) + ba.y, 0.f);
  v[2] = fmaxf(fmaf(sw, (float)sa[2], (float)(a0[2] + a1[2])) + ba.z, 0.f);
  v[3] = fmaxf(fmaf(sw, (float)sa[3], (float)(a0[3] + a1[3])) + ba.w, 0.f);
  v[4] = fmaxf(fmaf(sw, (float)sb[0], (float)(a0[4] + a1[4])) + bb.x, 0.f);
  v[5] = fmaxf(fmaf(sw, (float)sb[1], (float)(a0[5] + a1[5])) + bb.y, 0.f);
  v[6] = fmaxf(fmaf(sw, (float)sb[2], (float)(a0[6] + a1[6])) + bb.z, 0.f);
  v[7] = fmaxf(fmaf(sw, (float)sb[3], (float)(a0[7] + a1[7])) + bb.w, 0.f);

  size_t o = (size_t)n * H_DIM + c0;
  u16 hb[8], lb2[8];
#pragma unroll
  for (int k = 0; k < 8; ++k) {
    hb[k] = f2bf(v[k]);
    lb2[k] = f2bf(v[k] - bf2f(hb[k]));
  }
  uint2 p;
  p.x = (u32)hb[0] | ((u32)hb[1] << 16);
  p.y = (u32)hb[2] | ((u32)hb[3] << 16);
  *(uint2*)(Shi + o) = p;
  p.x = (u32)hb[4] | ((u32)hb[5] << 16);
  p.y = (u32)hb[6] | ((u32)hb[7] << 16);
  *(uint2*)(Shi + o + 256) = p;
  p.x = (u32)lb2[0] | ((u32)lb2[1] << 16);
  p.y = (u32)lb2[2] | ((u32)lb2[3] << 16);
  *(uint2*)(Slo + o) = p;
  p.x = (u32)lb2[4] | ((u32)lb2[5] << 16);
  p.y = (u32)lb2[6] | ((u32)lb2[7] << 16);
  *(uint2*)(Slo + o + 256) = p;

  if (FINAL) {
    float4 la = *(const float4*)(lw + c0);
    float4 lbv = *(const float4*)(lw + 256 + c0);
    float s = v[0] * la.x + v[1] * la.y + v[2] * la.z + v[3] * la.w +
              v[4] * lbv.x + v[5] * lbv.y + v[6] * lbv.z + v[7] * lbv.w;
#pragma unroll
    for (int off2 = 32; off2 > 0; off2 >>= 1) s += __shfl_down(s, off2, 64);
    if (lane == 0) out[n] = s + lb[0];
  }
}

// ---------------- launch ----------------
extern "C" void kernel_launch(void* const* d_in, const int* in_sizes, int n_in,
                              void* d_out, int out_size, void* d_ws, size_t ws_size,
                              hipStream_t stream) {
  const float* xs = (const float*)d_in[0];
  const int* ei = (const int*)d_in[1];
  const float* ew = (const float*)d_in[2];
  const float* W_ih = (const float*)d_in[3];
  const float* W_hh = (const float*)d_in[4];
  const float* b_ih = (const float*)d_in[5];
  const float* b_hh = (const float*)d_in[6];
  const float* conv_W = (const float*)d_in[7];
  const float* conv_b = (const float*)d_in[8];
  const float* lin_W = (const float*)d_in[9];
  const float* lin_b = (const float*)d_in[10];
  float* out = (float*)d_out;

  const int* row = ei;
  const int* col = ei + E_EDGES;

  char* ws = (char*)d_ws;
  size_t off = 0;
  auto alloc = [&](size_t bytes) -> void* {
    void* p = ws + off;
    off += (bytes + 255) & ~(size_t)255;
    return p;
  };
  u16* S_hi = (u16*)alloc((size_t)MP * H_DIM * 2);  // h state splits
  u16* S_lo = (u16*)alloc((size_t)MP * H_DIM * 2);
  u16* G_hi = (u16*)alloc((size_t)MP * H_DIM * 2);  // gate / agg0 out
  u16* G_lo = (u16*)alloc((size_t)MP * H_DIM * 2);
  _Float16* hW16 = (_Float16*)alloc((size_t)MP * H_DIM * 2);
  u16* xs_hi = (u16*)alloc((size_t)T_STEPS * MP * D_IN * 2);
  u16* xs_lo = (u16*)alloc((size_t)T_STEPS * MP * D_IN * 2);
  u16* WihG_hi = (u16*)alloc((size_t)H3 * D_IN * 2);
  u16* WihG_lo = (u16*)alloc((size_t)H3 * D_IN * 2);
  u16* WhhG_hi = (u16*)alloc((size_t)H3 * H_DIM * 2);
  u16* WhhG_lo = (u16*)alloc((size_t)H3 * H_DIM * 2);
  u16* Wc_hi = (u16*)alloc((size_t)NUM_CONVS * H_DIM * H_DIM * 2);
  u16* Wc_lo = (u16*)alloc((size_t)NUM_CONVS * H_DIM * H_DIM * 2);
  float* bihg = (float*)alloc(H3 * 4);
  float* bhhg = (float*)alloc(H3 * 4);
  float* dinv = (float*)alloc(N_NODES * 4);
  float* selfw = (float*)alloc(N_NODES * 4);
  float* csr_norm = (float*)alloc(E_EDGES * 4);
  int* csr_row = (int*)alloc(E_EDGES * 4);
  int* offsets = (int*)alloc((N_NODES + 1) * 4);
  int* counts = (int*)alloc(N_NODES * 4);
  int* cursor = (int*)alloc(N_NODES * 4);

  hipMemsetAsync(S_hi, 0, (size_t)MP * H_DIM * 2, stream);
  hipMemsetAsync(S_lo, 0, (size_t)MP * H_DIM * 2, stream);
  hipMemsetAsync(G_hi, 0, (size_t)MP * H_DIM * 2, stream);
  hipMemsetAsync(G_lo, 0, (size_t)MP * H_DIM * 2, stream);
  hipMemsetAsync(hW16, 0, (size_t)MP * H_DIM * 2, stream);
  hipMemsetAsync(dinv, 0, N_NODES * 4, stream);
  hipMemsetAsync(counts, 0, N_NODES * 4, stream);
  hipMemsetAsync(cursor, 0, N_NODES * 4, stream);

  // one-time preprocessing
  deg_kernel<<<(E_EDGES + 255) / 256, 256, 0, stream>>>(col, ew, dinv, counts);
  dinv_kernel<<<(N_NODES + 255) / 256, 256, 0, stream>>>(dinv, selfw);
  scan_kernel<<<1, 1024, 0, stream>>>(counts, offsets, N_NODES);
  scatter_kernel<<<(E_EDGES + 255) / 256, 256, 0, stream>>>(row, col, ew, dinv, offsets,
                                                            cursor, csr_row, csr_norm);
  split_grouped<<<(H3 * D_IN + 255) / 256, 256, 0, stream>>>(W_ih, WihG_hi, WihG_lo, D_IN);
  split_grouped<<<(H3 * H_DIM + 255) / 256, 256, 0, stream>>>(W_hh, WhhG_hi, WhhG_lo, H_DIM);
  bias_grouped<<<(H3 + 255) / 256, 256, 0, stream>>>(b_ih, b_hh, bihg, bhhg);
  split_convw<<<(NUM_CONVS * H_DIM * H_DIM + 255) / 256, 256, 0, stream>>>(conv_W, Wc_hi, Wc_lo);
  split_xs<<<(T_STEPS * MP * D_IN / 4 + 255) / 256, 256, 0, stream>>>(xs, xs_hi, xs_lo);

  dim3 blk(256);
  dim3 g_gru(16, MP / 128);       // 2 jb per block x 79 row-blocks
  dim3 g_conv(H_DIM / 128, MP / 64);  // 4 x 158 = 632 blocks
  int g_agg = (N_NODES + 3) / 4;

  for (int t = 0; t < T_STEPS; ++t) {
    // fused: gi + gh GEMMs + GRU gate -> G splits
    gru_fused<<<g_gru, blk, 0, stream>>>(
        xs_hi + (size_t)t * MP * D_IN, xs_lo + (size_t)t * MP * D_IN,
        S_hi, S_lo, WihG_hi, WihG_lo, WhhG_hi, WhhG_lo, bihg, bhhg, G_hi, G_lo);
    // conv0: hW16 = G @ Wc0 ; agg0 -> G
    gemm_conv<<<g_conv, blk, 0, stream>>>(G_hi, G_lo, Wc_hi, Wc_lo, hW16,
                                          N_NODES, H_DIM, H_DIM);
    agg_kernel<false><<<g_agg, 256, 0, stream>>>(
        hW16, csr_row, csr_norm, offsets, selfw, conv_b, G_hi, G_lo,
        nullptr, nullptr, nullptr);
    // conv1: hW16 = G @ Wc1 ; agg1(final) -> S state + fused linear
    gemm_conv<<<g_conv, blk, 0, stream>>>(
        G_hi, G_lo, Wc_hi + (size_t)H_DIM * H_DIM, Wc_lo + (size_t)H_DIM * H_DIM, hW16,
        N_NODES, H_DIM, H_DIM);
    agg_kernel<true><<<g_agg, 256, 0, stream>>>(
        hW16, csr_row, csr_norm, offsets, selfw, conv_b + H_DIM, S_hi, S_lo,
        lin_W, lin_b, out + (size_t)t * N_NODES);
  }
}

// Round 7
// 2476.337 us; speedup vs baseline: 1.0281x; 1.0281x over previous
//
#include <hip/hip_runtime.h>
#include <math.h>

#define T_STEPS 12
#define N_NODES 10000
#define MP 10112  // 79*128, padded M
#define D_IN 256
#define H_DIM 512
#define H3 1536
#define E_EDGES 160000
#define NUM_CONVS 2

typedef __bf16 bf16x8 __attribute__((ext_vector_type(8)));
typedef float floatx4 __attribute__((ext_vector_type(4)));
typedef _Float16 f16x4 __attribute__((ext_vector_type(4)));
typedef unsigned short u16;
typedef unsigned int u32;

__device__ __forceinline__ u16 f2bf(float f) {
  unsigned int u = __float_as_uint(f);
  u += 0x7FFFu + ((u >> 16) & 1u);  // round-nearest-even (no NaN inputs)
  return (u16)(u >> 16);
}
__device__ __forceinline__ float bf2f(u16 s) {
  return __uint_as_float(((unsigned int)s) << 16);
}
__device__ __forceinline__ float sigmoid_f(float x) {
  return __builtin_amdgcn_rcpf(1.0f + __expf(-x));
}
__device__ __forceinline__ float tanh_f(float x) {
  return 1.0f - 2.0f * __builtin_amdgcn_rcpf(1.0f + __expf(2.0f * x));
}

__device__ __forceinline__ void glds16(const void* g, void* l) {
  __builtin_amdgcn_global_load_lds(
      (const __attribute__((address_space(1))) unsigned int*)g,
      (__attribute__((address_space(3))) unsigned int*)l, 16, 0, 0);
}

#define MFMA16(a, b, c) __builtin_amdgcn_mfma_f32_16x16x32_bf16((a), (b), (c), 0, 0, 0)

// ============ fused GRU: verified 2-barrier structure + XCD swizzle =========
// (round-4 lesson: LDS double-buffer halves block residency -> net loss; the
// baseline single-buffer 28KB keeps 5 blocks/CU and inter-block overlap does
// the pipelining. Swizzle kept: FETCH_SIZE 145->76 MB confirmed.)
__global__ __launch_bounds__(256) void gru_fused(
    const u16* __restrict__ Xhi, const u16* __restrict__ Xlo,      // (MP,256)
    const u16* __restrict__ Shi_in, const u16* __restrict__ Slo_in,// (MP,512)
    const u16* __restrict__ Bxh, const u16* __restrict__ Bxl,      // WihG (1536,256)
    const u16* __restrict__ Bhh, const u16* __restrict__ Bhl,      // WhhG (1536,512)
    const float* __restrict__ bihg, const float* __restrict__ bhhg,
    u16* __restrict__ Ghi, u16* __restrict__ Glo) {
  __shared__ u16 As[2][4096];  // 128 rows x 32 k, hi/lo, swizzled 16B slots
  __shared__ u16 Bs[2][3072];  // 96 rows x 32 k
  const int tid = threadIdx.x;
  const int lane = tid & 63;
  const int wave = tid >> 6;
  // T1: XCD-chunked swizzle; 1264 blocks = 8 * 158 (exactly divisible)
  const int bid = blockIdx.y * 16 + blockIdx.x;
  const int lid = (bid & 7) * 158 + (bid >> 3);
  const int bx = lid & 15, by = lid >> 4;
  const int rbase = by * 128;
  const int cbase = bx * 96;

  // slot decompositions (K-independent)
  const int sa1 = tid, sa2 = tid + 256;
  const int ra1 = sa1 >> 2, ca1 = (sa1 & 3) ^ ((ra1 >> 1) & 3);
  const int ra2 = sa2 >> 2, ca2 = (sa2 & 3) ^ ((ra2 >> 1) & 3);
  const int la1 = (sa1 >> 6) << 9;
  const int la2 = (sa2 >> 6) << 9;
  const int sb1 = tid;
  const int rb1 = sb1 >> 2, cb1 = (sb1 & 3) ^ ((rb1 >> 1) & 3);
  const int lb1 = (sb1 >> 6) << 9;
  const int sb2 = 256 + tid;
  const int rb2 = sb2 >> 2, cb2 = (sb2 & 3) ^ ((rb2 >> 1) & 3);
  const int lb2 = (sb2 >> 6) << 9;

  const int wr = (wave >> 1) * 64;
  const int wc = (wave & 1) * 48;
  const int lrow = lane & 15;
  const int kq = lane >> 4;
  const int swz = kq ^ ((lrow >> 1) & 3);
  const int aoff = (wr + lrow) * 32 + swz * 8;
  const int boff = (wc + lrow) * 32 + swz * 8;

  floatx4 acc[4][4];  // [row-frag][gate: 0=r 1=z 2=ni 3=nh]
#pragma unroll
  for (int i = 0; i < 4; ++i)
#pragma unroll
    for (int g = 0; g < 4; ++g) acc[i][g] = (floatx4){0.f, 0.f, 0.f, 0.f};

  // ---------------- phase 1: x_t @ W_ih^T, K=256 ----------------
  {
    const u16* pa1 = Xhi + (size_t)(rbase + ra1) * 256 + ca1 * 8;
    const u16* pa2 = Xhi + (size_t)(rbase + ra2) * 256 + ca2 * 8;
    const u16* pl1 = Xlo + (size_t)(rbase + ra1) * 256 + ca1 * 8;
    const u16* pl2 = Xlo + (size_t)(rbase + ra2) * 256 + ca2 * 8;
    const u16* pb1 = Bxh + (size_t)(cbase + rb1) * 256 + cb1 * 8;
    const u16* pc1 = Bxl + (size_t)(cbase + rb1) * 256 + cb1 * 8;
    const u16* pb2 = Bxh + (size_t)(cbase + rb2) * 256 + cb2 * 8;
    const u16* pc2 = Bxl + (size_t)(cbase + rb2) * 256 + cb2 * 8;
    for (int kt = 0; kt < 256; kt += 32) {
      glds16(pa1 + kt, &As[0][la1]);
      glds16(pa2 + kt, &As[0][la2]);
      glds16(pl1 + kt, &As[1][la1]);
      glds16(pl2 + kt, &As[1][la2]);
      glds16(pb1 + kt, &Bs[0][lb1]);
      glds16(pc1 + kt, &Bs[1][lb1]);
      if (tid < 128) {
        glds16(pb2 + kt, &Bs[0][lb2]);
        glds16(pc2 + kt, &Bs[1][lb2]);
      }
      __syncthreads();
      bf16x8 ah[4], bh[3], bl[3];
#pragma unroll
      for (int i = 0; i < 4; ++i) ah[i] = *(const bf16x8*)&As[0][aoff + i * 512];
#pragma unroll
      for (int g = 0; g < 3; ++g) bh[g] = *(const bf16x8*)&Bs[0][boff + g * 512];
#pragma unroll
      for (int i = 0; i < 4; ++i)
#pragma unroll
        for (int g = 0; g < 3; ++g)
          acc[i][g] = MFMA16(ah[i], bh[g], acc[i][g]);
#pragma unroll
      for (int g = 0; g < 3; ++g) bl[g] = *(const bf16x8*)&Bs[1][boff + g * 512];
#pragma unroll
      for (int i = 0; i < 4; ++i)
#pragma unroll
        for (int g = 0; g < 3; ++g)
          acc[i][g] = MFMA16(ah[i], bl[g], acc[i][g]);
#pragma unroll
      for (int i = 0; i < 4; ++i) {
        bf16x8 al = *(const bf16x8*)&As[1][aoff + i * 512];
#pragma unroll
        for (int g = 0; g < 3; ++g)
          acc[i][g] = MFMA16(al, bh[g], acc[i][g]);
      }
      __syncthreads();
    }
  }
  // ---------------- phase 2: h @ W_hh^T, K=512; n-group -> acc[.][3] -------
  {
    const u16* pa1 = Shi_in + (size_t)(rbase + ra1) * 512 + ca1 * 8;
    const u16* pa2 = Shi_in + (size_t)(rbase + ra2) * 512 + ca2 * 8;
    const u16* pl1 = Slo_in + (size_t)(rbase + ra1) * 512 + ca1 * 8;
    const u16* pl2 = Slo_in + (size_t)(rbase + ra2) * 512 + ca2 * 8;
    const u16* pb1 = Bhh + (size_t)(cbase + rb1) * 512 + cb1 * 8;
    const u16* pc1 = Bhl + (size_t)(cbase + rb1) * 512 + cb1 * 8;
    const u16* pb2 = Bhh + (size_t)(cbase + rb2) * 512 + cb2 * 8;
    const u16* pc2 = Bhl + (size_t)(cbase + rb2) * 512 + cb2 * 8;
    for (int kt = 0; kt < 512; kt += 32) {
      glds16(pa1 + kt, &As[0][la1]);
      glds16(pa2 + kt, &As[0][la2]);
      glds16(pl1 + kt, &As[1][la1]);
      glds16(pl2 + kt, &As[1][la2]);
      glds16(pb1 + kt, &Bs[0][lb1]);
      glds16(pc1 + kt, &Bs[1][lb1]);
      if (tid < 128) {
        glds16(pb2 + kt, &Bs[0][lb2]);
        glds16(pc2 + kt, &Bs[1][lb2]);
      }
      __syncthreads();
      bf16x8 ah[4], bh[3], bl[3];
#pragma unroll
      for (int i = 0; i < 4; ++i) ah[i] = *(const bf16x8*)&As[0][aoff + i * 512];
#pragma unroll
      for (int g = 0; g < 3; ++g) bh[g] = *(const bf16x8*)&Bs[0][boff + g * 512];
#pragma unroll
      for (int i = 0; i < 4; ++i) {
        acc[i][0] = MFMA16(ah[i], bh[0], acc[i][0]);
        acc[i][1] = MFMA16(ah[i], bh[1], acc[i][1]);
        acc[i][3] = MFMA16(ah[i], bh[2], acc[i][3]);
      }
#pragma unroll
      for (int g = 0; g < 3; ++g) bl[g] = *(const bf16x8*)&Bs[1][boff + g * 512];
#pragma unroll
      for (int i = 0; i < 4; ++i) {
        acc[i][0] = MFMA16(ah[i], bl[0], acc[i][0]);
        acc[i][1] = MFMA16(ah[i], bl[1], acc[i][1]);
        acc[i][3] = MFMA16(ah[i], bl[2], acc[i][3]);
      }
#pragma unroll
      for (int i = 0; i < 4; ++i) {
        bf16x8 al = *(const bf16x8*)&As[1][aoff + i * 512];
        acc[i][0] = MFMA16(al, bh[0], acc[i][0]);
        acc[i][1] = MFMA16(al, bh[1], acc[i][1]);
        acc[i][3] = MFMA16(al, bh[2], acc[i][3]);
      }
      __syncthreads();
    }
  }

  // ---------------- epilogue: GRU gate in registers ----------------
  const int c0g = cbase + wc + lrow;
  const int j = (((bx << 1) | (wave & 1)) << 4) | lrow;
  const float brz0 = bihg[c0g] + bhhg[c0g];
  const float brz1 = bihg[c0g + 16] + bhhg[c0g + 16];
  const float bin = bihg[c0g + 32];
  const float bhn = bhhg[c0g + 32];
#pragma unroll
  for (int i = 0; i < 4; ++i) {
    int r0 = rbase + wr + i * 16 + kq * 4;
#pragma unroll
    for (int rr = 0; rr < 4; ++rr) {
      int row = r0 + rr;
      if (row >= N_NODES) continue;
      float r = sigmoid_f(acc[i][0][rr] + brz0);
      float z = sigmoid_f(acc[i][1][rr] + brz1);
      float nn = tanh_f(acc[i][2][rr] + bin + r * (acc[i][3][rr] + bhn));
      size_t o = (size_t)row * H_DIM + j;
      float hp = bf2f(Shi_in[o]) + bf2f(Slo_in[o]);
      float hv = (1.0f - z) * nn + z * hp;
      u16 hb = f2bf(hv);
      Ghi[o] = hb;
      Glo[o] = f2bf(hv - bf2f(hb));
    }
  }
}

// One conv K-step: 3 sub-phases of 8 MFMA each. (round-4 verified: pipelined
// conv improved the non-gru time by ~360us; 24KB dbuf keeps ~6 blocks/CU)
__device__ __forceinline__ void conv_kstep(const u16 (&As)[2][2][2048],
                                           const u16 (&Bs)[2][2][4096], int cur,
                                           int aoff, int boff,
                                           floatx4 (&acc)[2][4]) {
  bf16x8 ah[2], bh[4], bl[4], al[2];
#pragma unroll
  for (int i = 0; i < 2; ++i) ah[i] = *(const bf16x8*)&As[cur][0][aoff + i * 512];
#pragma unroll
  for (int jj = 0; jj < 4; ++jj) bh[jj] = *(const bf16x8*)&Bs[cur][0][boff + jj * 512];
  __builtin_amdgcn_s_setprio(1);
#pragma unroll
  for (int i = 0; i < 2; ++i)
#pragma unroll
    for (int jj = 0; jj < 4; ++jj) acc[i][jj] = MFMA16(ah[i], bh[jj], acc[i][jj]);
  __builtin_amdgcn_s_setprio(0);
  __builtin_amdgcn_s_barrier();
#pragma unroll
  for (int jj = 0; jj < 4; ++jj) bl[jj] = *(const bf16x8*)&Bs[cur][1][boff + jj * 512];
  __builtin_amdgcn_s_setprio(1);
#pragma unroll
  for (int i = 0; i < 2; ++i)
#pragma unroll
    for (int jj = 0; jj < 4; ++jj) acc[i][jj] = MFMA16(ah[i], bl[jj], acc[i][jj]);
  __builtin_amdgcn_s_setprio(0);
  __builtin_amdgcn_s_barrier();
#pragma unroll
  for (int i = 0; i < 2; ++i) al[i] = *(const bf16x8*)&As[cur][1][aoff + i * 512];
  __builtin_amdgcn_s_setprio(1);
#pragma unroll
  for (int i = 0; i < 2; ++i)
#pragma unroll
    for (int jj = 0; jj < 4; ++jj) acc[i][jj] = MFMA16(al[i], bh[jj], acc[i][jj]);
  __builtin_amdgcn_s_setprio(0);
  __builtin_amdgcn_s_barrier();
}

// ============ conv GEMM: 64x128 bf16x3, pipelined, fp16 output ==============
__global__ __launch_bounds__(256) void gemm_conv(
    const u16* __restrict__ Ahi, const u16* __restrict__ Alo,
    const u16* __restrict__ Bhi, const u16* __restrict__ Blo,
    _Float16* __restrict__ C, int M, int Nn, int K) {
  __shared__ u16 As[2][2][2048];  // [buf][hi/lo] 64 rows x 32 k
  __shared__ u16 Bs[2][2][4096];  // [buf][hi/lo] 128 rows x 32 k
  const int tid = threadIdx.x;
  const int lane = tid & 63;
  const int wave = tid >> 6;
  // T1: XCD-chunked swizzle; 632 blocks = 8 * 79
  const int bid = blockIdx.y * 4 + blockIdx.x;
  const int lid = (bid & 7) * 79 + (bid >> 3);
  const int bx = lid & 3, by = lid >> 2;
  const int rbase = by * 64;
  const int cbase = bx * 128;

  const int sa = tid;
  const int ra = sa >> 2, ca = (sa & 3) ^ ((ra >> 1) & 3);
  const int la = (sa >> 6) << 9;
  const int sb1 = tid, sb2 = tid + 256;
  const int rb1 = sb1 >> 2, cb1 = (sb1 & 3) ^ ((rb1 >> 1) & 3);
  const int rb2 = sb2 >> 2, cb2 = (sb2 & 3) ^ ((rb2 >> 1) & 3);
  const int lb1 = (sb1 >> 6) << 9, lb2 = (sb2 >> 6) << 9;
  const size_t oA = (size_t)(rbase + ra) * K + ca * 8;
  const size_t oB1 = (size_t)(cbase + rb1) * K + cb1 * 8;
  const size_t oB2 = (size_t)(cbase + rb2) * K + cb2 * 8;

  const int wr = (wave >> 1) * 32;
  const int wc = (wave & 1) * 64;
  const int lrow = lane & 15;
  const int kq = lane >> 4;
  const int swz = kq ^ ((lrow >> 1) & 3);
  const int aoff = (wr + lrow) * 32 + swz * 8;
  const int boff = (wc + lrow) * 32 + swz * 8;

  auto stage = [&](int buf, int t) {  // 6 loads per thread, uniform
    const int kt = t * 32;
    glds16(Ahi + oA + kt, &As[buf][0][la]);
    glds16(Alo + oA + kt, &As[buf][1][la]);
    glds16(Bhi + oB1 + kt, &Bs[buf][0][lb1]);
    glds16(Bhi + oB2 + kt, &Bs[buf][0][lb2]);
    glds16(Blo + oB1 + kt, &Bs[buf][1][lb1]);
    glds16(Blo + oB2 + kt, &Bs[buf][1][lb2]);
  };

  floatx4 acc[2][4];
#pragma unroll
  for (int i = 0; i < 2; ++i)
#pragma unroll
    for (int jj = 0; jj < 4; ++jj) acc[i][jj] = (floatx4){0.f, 0.f, 0.f, 0.f};

  const int NT = K >> 5;  // 16
  stage(0, 0);
  stage(1, 1);
  int cur = 0;
  for (int t = 0; t < NT; ++t) {
    if (t < NT - 1) asm volatile("s_waitcnt vmcnt(6)" ::: "memory");
    else            asm volatile("s_waitcnt vmcnt(0)" ::: "memory");
    __builtin_amdgcn_s_barrier();
    __builtin_amdgcn_sched_barrier(0);
    conv_kstep(As, Bs, cur, aoff, boff, acc);
    __builtin_amdgcn_sched_barrier(0);
    if (t + 2 < NT) stage(cur, t + 2);
    cur ^= 1;
  }

#pragma unroll
  for (int jj = 0; jj < 4; ++jj) {
    int col = cbase + wc + jj * 16 + lrow;
#pragma unroll
    for (int i = 0; i < 2; ++i) {
      int r0 = rbase + wr + i * 16 + kq * 4;
#pragma unroll
      for (int rr = 0; rr < 4; ++rr) {
        int row = r0 + rr;
        if (row < M) C[(size_t)row * Nn + col] = (_Float16)acc[i][jj][rr];
      }
    }
  }
}

// ---------------- split / preprocessing kernels ----------------
__global__ void split_grouped(const float* __restrict__ W, u16* __restrict__ hi,
                              u16* __restrict__ lo, int K) {
  int i = blockIdx.x * 256 + threadIdx.x;
  if (i >= H3 * K) return;
  int r3h = i / K, k = i - r3h * K;
  int g = r3h >> 9, j = r3h & 511;
  int nr = ((j >> 4) * 48) + (g << 4) + (j & 15);
  float v = W[i];
  u16 h = f2bf(v);
  size_t o = (size_t)nr * K + k;
  hi[o] = h;
  lo[o] = f2bf(v - bf2f(h));
}

__global__ void bias_grouped(const float* __restrict__ bih, const float* __restrict__ bhh,
                             float* __restrict__ bihg, float* __restrict__ bhhg) {
  int n = blockIdx.x * 256 + threadIdx.x;
  if (n >= H3) return;
  int g = n >> 9, j = n & 511;
  int nr = ((j >> 4) * 48) + (g << 4) + (j & 15);
  bihg[nr] = bih[n];
  bhhg[nr] = bhh[n];
}

__global__ void split_convw(const float* __restrict__ W, u16* __restrict__ hi,
                            u16* __restrict__ lo) {
  int o = blockIdx.x * 256 + threadIdx.x;
  if (o >= NUM_CONVS * H_DIM * H_DIM) return;
  int k = o & 511, j = (o >> 9) & 511, l = o >> 18;
  float v = W[(size_t)l * H_DIM * H_DIM + (size_t)k * H_DIM + j];
  u16 h = f2bf(v);
  hi[o] = h;
  lo[o] = f2bf(v - bf2f(h));
}

__global__ void split_xs(const float* __restrict__ xs, u16* __restrict__ hi,
                         u16* __restrict__ lo) {
  const int QP = MP * D_IN / 4;
  int q = blockIdx.x * 256 + threadIdx.x;
  if (q >= T_STEPS * QP) return;
  int t = q / QP;
  int rem = (q - t * QP) * 4;
  size_t o = (size_t)t * MP * D_IN + rem;
  uint2 hp = make_uint2(0u, 0u), lp = make_uint2(0u, 0u);
  if (rem < N_NODES * D_IN) {
    float4 v = *(const float4*)(xs + (size_t)t * N_NODES * D_IN + rem);
    float vv[4] = {v.x, v.y, v.z, v.w};
    u16 hb[4], lb[4];
#pragma unroll
    for (int k = 0; k < 4; ++k) {
      hb[k] = f2bf(vv[k]);
      lb[k] = f2bf(vv[k] - bf2f(hb[k]));
    }
    hp.x = (u32)hb[0] | ((u32)hb[1] << 16);
    hp.y = (u32)hb[2] | ((u32)hb[3] << 16);
    lp.x = (u32)lb[0] | ((u32)lb[1] << 16);
    lp.y = (u32)lb[2] | ((u32)lb[3] << 16);
  }
  *(uint2*)(hi + o) = hp;
  *(uint2*)(lo + o) = lp;
}

__global__ void deg_kernel(const int* __restrict__ col, const float* __restrict__ w,
                           float* __restrict__ deg, int* __restrict__ counts) {
  int e = blockIdx.x * blockDim.x + threadIdx.x;
  if (e >= E_EDGES) return;
  int c = col[e];
  atomicAdd(&deg[c], w[e]);
  atomicAdd(&counts[c], 1);
}

__global__ void dinv_kernel(float* __restrict__ deg_dinv, float* __restrict__ selfw) {
  int n = blockIdx.x * blockDim.x + threadIdx.x;
  if (n >= N_NODES) return;
  float d = deg_dinv[n] + 1.0f;
  float di = 1.0f / sqrtf(d);
  deg_dinv[n] = di;
  selfw[n] = 1.0f / d;
}

__global__ __launch_bounds__(1024) void scan_kernel(const int* __restrict__ counts,
                                                    int* __restrict__ offsets, int n) {
  __shared__ int smem[1024];
  __shared__ int carry_s;
  if (threadIdx.x == 0) carry_s = 0;
  __syncthreads();
  for (int base = 0; base < n; base += 1024) {
    int i = base + threadIdx.x;
    int v = (i < n) ? counts[i] : 0;
    smem[threadIdx.x] = v;
    __syncthreads();
    for (int off = 1; off < 1024; off <<= 1) {
      int t = (threadIdx.x >= off) ? smem[threadIdx.x - off] : 0;
      __syncthreads();
      smem[threadIdx.x] += t;
      __syncthreads();
    }
    if (i < n) offsets[i] = carry_s + smem[threadIdx.x] - v;
    int total = smem[1023];
    __syncthreads();
    if (threadIdx.x == 0) carry_s += total;
    __syncthreads();
  }
  if (threadIdx.x == 0) offsets[n] = carry_s;
}

__global__ void scatter_kernel(const int* __restrict__ row, const int* __restrict__ col,
                               const float* __restrict__ w, const float* __restrict__ dinv,
                               const int* __restrict__ offsets, int* __restrict__ cursor,
                               int* __restrict__ csr_row, float* __restrict__ csr_norm) {
  int e = blockIdx.x * blockDim.x + threadIdx.x;
  if (e >= E_EDGES) return;
  int r = row[e], c = col[e];
  float nrm = dinv[r] * w[e] * dinv[c];
  int pos = offsets[c] + atomicAdd(&cursor[c], 1);
  csr_row[pos] = r;
  csr_norm[pos] = nrm;
}

// ---------------- GCN aggregation (fp16 hW) + relu + split (+ final lin) ---
__device__ __forceinline__ void fma8h(double* a, float w, const _Float16* p) {
  f16x4 x = *(const f16x4*)p;
  f16x4 y = *(const f16x4*)(p + 256);
  double wd = (double)w;
  a[0] = fma(wd, (double)(float)x[0], a[0]);
  a[1] = fma(wd, (double)(float)x[1], a[1]);
  a[2] = fma(wd, (double)(float)x[2], a[2]);
  a[3] = fma(wd, (double)(float)x[3], a[3]);
  a[4] = fma(wd, (double)(float)y[0], a[4]);
  a[5] = fma(wd, (double)(float)y[1], a[5]);
  a[6] = fma(wd, (double)(float)y[2], a[6]);
  a[7] = fma(wd, (double)(float)y[3], a[7]);
}

template <bool FINAL>
__global__ __launch_bounds__(256) void agg_kernel(
    const _Float16* __restrict__ hW, const int* __restrict__ csr_row,
    const float* __restrict__ csr_norm, const int* __restrict__ offsets,
    const float* __restrict__ selfw, const float* __restrict__ bias,
    u16* __restrict__ Shi, u16* __restrict__ Slo,
    const float* __restrict__ lw, const float* __restrict__ lb,
    float* __restrict__ out) {
  const int n = (blockIdx.x << 2) | (threadIdx.x >> 6);
  const int lane = threadIdx.x & 63;
  if (n >= N_NODES) return;
  const int c0 = lane << 2;
  const int beg = offsets[n], end = offsets[n + 1];
  double a0[8] = {}, a1[8] = {};
  int j = beg;
  for (; j + 4 <= end; j += 4) {
    int r0 = csr_row[j], r1 = csr_row[j + 1], r2 = csr_row[j + 2], r3 = csr_row[j + 3];
    float w0 = csr_norm[j], w1 = csr_norm[j + 1], w2 = csr_norm[j + 2], w3 = csr_norm[j + 3];
    fma8h(a0, w0, hW + (size_t)r0 * H_DIM + c0);
    fma8h(a1, w1, hW + (size_t)r1 * H_DIM + c0);
    fma8h(a0, w2, hW + (size_t)r2 * H_DIM + c0);
    fma8h(a1, w3, hW + (size_t)r3 * H_DIM + c0);
  }
  for (; j < end; ++j) fma8h(a0, csr_norm[j], hW + (size_t)csr_row[j] * H_DIM + c0);

  const float sw = selfw[n];
  const _Float16* ps = hW + (size_t)n * H_DIM + c0;
  f16x4 sa = *(const f16x4*)ps;
  f16x4 sb = *(const f16x4*)(ps + 256);
  float4 ba = *(const float4*)(bias + c0);
  float4 bb = *(const float4*)(bias + 256 + c0);
  float v[8];
  v[0] = fmaxf(fmaf(sw, (float)sa[0], (float)(a0[0] + a1[0])) + ba.x, 0.f);
  v[1] = fmaxf(fmaf(sw, (float)sa[1], (float)(a0[1] + a1[1])) + ba.y, 0.f);
  v[2] = fmaxf(fmaf(sw, (float)sa[2], (float)(a0[2] + a1[2])) + ba.z, 0.f);
  v[3] = fmaxf(fmaf(sw, (float)sa[3], (float)(a0[3] + a1[3])) + ba.w, 0.f);
  v[4] = fmaxf(fmaf(sw, (float)sb[0], (float)(a0[4] + a1[4])) + bb.x, 0.f);
  v[5] = fmaxf(fmaf(sw, (float)sb[1], (float)(a0[5] + a1[5])) + bb.y, 0.f);
  v[6] = fmaxf(fmaf(sw, (float)sb[2], (float)(a0[6] + a1[6])) + bb.z, 0.f);
  v[7] = fmaxf(fmaf(sw, (float)sb[3], (float)(a0[7] + a1[7])) + bb.w, 0.f);

  size_t o = (size_t)n * H_DIM + c0;
  u16 hb[8], lb2[8];
#pragma unroll
  for (int k = 0; k < 8; ++k) {
    hb[k] = f2bf(v[k]);
    lb2[k] = f2bf(v[k] - bf2f(hb[k]));
  }
  uint2 p;
  p.x = (u32)hb[0] | ((u32)hb[1] << 16);
  p.y = (u32)hb[2] | ((u32)hb[3] << 16);
  *(uint2*)(Shi + o) = p;
  p.x = (u32)hb[4] | ((u32)hb[5] << 16);
  p.y = (u32)hb[6] | ((u32)hb[7] << 16);
  *(uint2*)(Shi + o + 256) = p;
  p.x = (u32)lb2[0] | ((u32)lb2[1] << 16);
  p.y = (u32)lb2[2] | ((u32)lb2[3] << 16);
  *(uint2*)(Slo + o) = p;
  p.x = (u32)lb2[4] | ((u32)lb2[5] << 16);
  p.y = (u32)lb2[6] | ((u32)lb2[7] << 16);
  *(uint2*)(Slo + o + 256) = p;

  if (FINAL) {
    float4 la = *(const float4*)(lw + c0);
    float4 lbv = *(const float4*)(lw + 256 + c0);
    float s = v[0] * la.x + v[1] * la.y + v[2] * la.z + v[3] * la.w +
              v[4] * lbv.x + v[5] * lbv.y + v[6] * lbv.z + v[7] * lbv.w;
#pragma unroll
    for (int off2 = 32; off2 > 0; off2 >>= 1) s += __shfl_down(s, off2, 64);
    if (lane == 0) out[n] = s + lb[0];
  }
}

// ---------------- launch ----------------
extern "C" void kernel_launch(void* const* d_in, const int* in_sizes, int n_in,
                              void* d_out, int out_size, void* d_ws, size_t ws_size,
                              hipStream_t stream) {
  const float* xs = (const float*)d_in[0];
  const int* ei = (const int*)d_in[1];
  const float* ew = (const float*)d_in[2];
  const float* W_ih = (const float*)d_in[3];
  const float* W_hh = (const float*)d_in[4];
  const float* b_ih = (const float*)d_in[5];
  const float* b_hh = (const float*)d_in[6];
  const float* conv_W = (const float*)d_in[7];
  const float* conv_b = (const float*)d_in[8];
  const float* lin_W = (const float*)d_in[9];
  const float* lin_b = (const float*)d_in[10];
  float* out = (float*)d_out;

  const int* row = ei;
  const int* col = ei + E_EDGES;

  char* ws = (char*)d_ws;
  size_t off = 0;
  auto alloc = [&](size_t bytes) -> void* {
    void* p = ws + off;
    off += (bytes + 255) & ~(size_t)255;
    return p;
  };
  u16* S_hi = (u16*)alloc((size_t)MP * H_DIM * 2);  // h state splits
  u16* S_lo = (u16*)alloc((size_t)MP * H_DIM * 2);
  u16* G_hi = (u16*)alloc((size_t)MP * H_DIM * 2);  // gate / agg0 out
  u16* G_lo = (u16*)alloc((size_t)MP * H_DIM * 2);
  _Float16* hW16 = (_Float16*)alloc((size_t)MP * H_DIM * 2);
  u16* xs_hi = (u16*)alloc((size_t)T_STEPS * MP * D_IN * 2);
  u16* xs_lo = (u16*)alloc((size_t)T_STEPS * MP * D_IN * 2);
  u16* WihG_hi = (u16*)alloc((size_t)H3 * D_IN * 2);
  u16* WihG_lo = (u16*)alloc((size_t)H3 * D_IN * 2);
  u16* WhhG_hi = (u16*)alloc((size_t)H3 * H_DIM * 2);
  u16* WhhG_lo = (u16*)alloc((size_t)H3 * H_DIM * 2);
  u16* Wc_hi = (u16*)alloc((size_t)NUM_CONVS * H_DIM * H_DIM * 2);
  u16* Wc_lo = (u16*)alloc((size_t)NUM_CONVS * H_DIM * H_DIM * 2);
  float* bihg = (float*)alloc(H3 * 4);
  float* bhhg = (float*)alloc(H3 * 4);
  float* dinv = (float*)alloc(N_NODES * 4);
  float* selfw = (float*)alloc(N_NODES * 4);
  float* csr_norm = (float*)alloc(E_EDGES * 4);
  int* csr_row = (int*)alloc(E_EDGES * 4);
  int* offsets = (int*)alloc((N_NODES + 1) * 4);
  int* counts = (int*)alloc(N_NODES * 4);
  int* cursor = (int*)alloc(N_NODES * 4);

  hipMemsetAsync(S_hi, 0, (size_t)MP * H_DIM * 2, stream);
  hipMemsetAsync(S_lo, 0, (size_t)MP * H_DIM * 2, stream);
  hipMemsetAsync(G_hi, 0, (size_t)MP * H_DIM * 2, stream);
  hipMemsetAsync(G_lo, 0, (size_t)MP * H_DIM * 2, stream);
  hipMemsetAsync(hW16, 0, (size_t)MP * H_DIM * 2, stream);
  hipMemsetAsync(dinv, 0, N_NODES * 4, stream);
  hipMemsetAsync(counts, 0, N_NODES * 4, stream);
  hipMemsetAsync(cursor, 0, N_NODES * 4, stream);

  // one-time preprocessing
  deg_kernel<<<(E_EDGES + 255) / 256, 256, 0, stream>>>(col, ew, dinv, counts);
  dinv_kernel<<<(N_NODES + 255) / 256, 256, 0, stream>>>(dinv, selfw);
  scan_kernel<<<1, 1024, 0, stream>>>(counts, offsets, N_NODES);
  scatter_kernel<<<(E_EDGES + 255) / 256, 256, 0, stream>>>(row, col, ew, dinv, offsets,
                                                            cursor, csr_row, csr_norm);
  split_grouped<<<(H3 * D_IN + 255) / 256, 256, 0, stream>>>(W_ih, WihG_hi, WihG_lo, D_IN);
  split_grouped<<<(H3 * H_DIM + 255) / 256, 256, 0, stream>>>(W_hh, WhhG_hi, WhhG_lo, H_DIM);
  bias_grouped<<<(H3 + 255) / 256, 256, 0, stream>>>(b_ih, b_hh, bihg, bhhg);
  split_convw<<<(NUM_CONVS * H_DIM * H_DIM + 255) / 256, 256, 0, stream>>>(conv_W, Wc_hi, Wc_lo);
  split_xs<<<(T_STEPS * MP * D_IN / 4 + 255) / 256, 256, 0, stream>>>(xs, xs_hi, xs_lo);

  dim3 blk(256);
  dim3 g_gru(16, MP / 128);       // 2 jb per block x 79 row-blocks
  dim3 g_conv(H_DIM / 128, MP / 64);  // 4 x 158 = 632 blocks
  int g_agg = (N_NODES + 3) / 4;

  for (int t = 0; t < T_STEPS; ++t) {
    // fused: gi + gh GEMMs + GRU gate -> G splits
    gru_fused<<<g_gru, blk, 0, stream>>>(
        xs_hi + (size_t)t * MP * D_IN, xs_lo + (size_t)t * MP * D_IN,
        S_hi, S_lo, WihG_hi, WihG_lo, WhhG_hi, WhhG_lo, bihg, bhhg, G_hi, G_lo);
    // conv0: hW16 = G @ Wc0 ; agg0 -> G
    gemm_conv<<<g_conv, blk, 0, stream>>>(G_hi, G_lo, Wc_hi, Wc_lo, hW16,
                                          N_NODES, H_DIM, H_DIM);
    agg_kernel<false><<<g_agg, 256, 0, stream>>>(
        hW16, csr_row, csr_norm, offsets, selfw, conv_b, G_hi, G_lo,
        nullptr, nullptr, nullptr);
    // conv1: hW16 = G @ Wc1 ; agg1(final) -> S state + fused linear
    gemm_conv<<<g_conv, blk, 0, stream>>>(
        G_hi, G_lo, Wc_hi + (size_t)H_DIM * H_DIM, Wc_lo + (size_t)H_DIM * H_DIM, hW16,
        N_NODES, H_DIM, H_DIM);
    agg_kernel<true><<<g_agg, 256, 0, stream>>>(
        hW16, csr_row, csr_norm, offsets, selfw, conv_b + H_DIM, S_hi, S_lo,
        lin_W, lin_b, out + (size_t)t * N_NODES);
  }
}

// Round 8
// 2440.372 us; speedup vs baseline: 1.0432x; 1.0147x over previous
//
#include <hip/hip_runtime.h>
#include <math.h>

#define T_STEPS 12
#define N_NODES 10000
#define MP 10112  // 79*128, padded M
#define D_IN 256
#define H_DIM 512
#define H3 1536
#define E_EDGES 160000
#define NUM_CONVS 2

typedef __bf16 bf16x8 __attribute__((ext_vector_type(8)));
typedef float floatx4 __attribute__((ext_vector_type(4)));
typedef _Float16 f16x4 __attribute__((ext_vector_type(4)));
typedef unsigned short u16;
typedef unsigned int u32;

__device__ __forceinline__ u16 f2bf(float f) {
  unsigned int u = __float_as_uint(f);
  u += 0x7FFFu + ((u >> 16) & 1u);  // round-nearest-even (no NaN inputs)
  return (u16)(u >> 16);
}
__device__ __forceinline__ float bf2f(u16 s) {
  return __uint_as_float(((unsigned int)s) << 16);
}
__device__ __forceinline__ float sigmoid_f(float x) {
  return __builtin_amdgcn_rcpf(1.0f + __expf(-x));
}
__device__ __forceinline__ float tanh_f(float x) {
  return 1.0f - 2.0f * __builtin_amdgcn_rcpf(1.0f + __expf(2.0f * x));
}

__device__ __forceinline__ void glds16(const void* g, void* l) {
  __builtin_amdgcn_global_load_lds(
      (const __attribute__((address_space(1))) unsigned int*)g,
      (__attribute__((address_space(3))) unsigned int*)l, 16, 0, 0);
}

#define MFMA16(a, b, c) __builtin_amdgcn_mfma_f32_16x16x32_bf16((a), (b), (c), 0, 0, 0)

// ============ fused GRU: verified 2-barrier structure + XCD swizzle =========
// (round-7 verified: 85 us/dispatch, MfmaUtil 33%, FETCH 60MB, 837 TF = ~93%
// of the m97-structure ceiling. Round-4 lesson: LDS dbuf halves residency ->
// net loss; single-buffer 28KB keeps 5 blocks/CU, inter-block overlap does
// the pipelining.)
__global__ __launch_bounds__(256) void gru_fused(
    const u16* __restrict__ Xhi, const u16* __restrict__ Xlo,      // (MP,256)
    const u16* __restrict__ Shi_in, const u16* __restrict__ Slo_in,// (MP,512)
    const u16* __restrict__ Bxh, const u16* __restrict__ Bxl,      // WihG (1536,256)
    const u16* __restrict__ Bhh, const u16* __restrict__ Bhl,      // WhhG (1536,512)
    const float* __restrict__ bihg, const float* __restrict__ bhhg,
    u16* __restrict__ Ghi, u16* __restrict__ Glo) {
  __shared__ u16 As[2][4096];  // 128 rows x 32 k, hi/lo, swizzled 16B slots
  __shared__ u16 Bs[2][3072];  // 96 rows x 32 k
  const int tid = threadIdx.x;
  const int lane = tid & 63;
  const int wave = tid >> 6;
  // T1: XCD-chunked swizzle; 1264 blocks = 8 * 158 (exactly divisible)
  const int bid = blockIdx.y * 16 + blockIdx.x;
  const int lid = (bid & 7) * 158 + (bid >> 3);
  const int bx = lid & 15, by = lid >> 4;
  const int rbase = by * 128;
  const int cbase = bx * 96;

  // slot decompositions (K-independent)
  const int sa1 = tid, sa2 = tid + 256;
  const int ra1 = sa1 >> 2, ca1 = (sa1 & 3) ^ ((ra1 >> 1) & 3);
  const int ra2 = sa2 >> 2, ca2 = (sa2 & 3) ^ ((ra2 >> 1) & 3);
  const int la1 = (sa1 >> 6) << 9;
  const int la2 = (sa2 >> 6) << 9;
  const int sb1 = tid;
  const int rb1 = sb1 >> 2, cb1 = (sb1 & 3) ^ ((rb1 >> 1) & 3);
  const int lb1 = (sb1 >> 6) << 9;
  const int sb2 = 256 + tid;
  const int rb2 = sb2 >> 2, cb2 = (sb2 & 3) ^ ((rb2 >> 1) & 3);
  const int lb2 = (sb2 >> 6) << 9;

  const int wr = (wave >> 1) * 64;
  const int wc = (wave & 1) * 48;
  const int lrow = lane & 15;
  const int kq = lane >> 4;
  const int swz = kq ^ ((lrow >> 1) & 3);
  const int aoff = (wr + lrow) * 32 + swz * 8;
  const int boff = (wc + lrow) * 32 + swz * 8;

  floatx4 acc[4][4];  // [row-frag][gate: 0=r 1=z 2=ni 3=nh]
#pragma unroll
  for (int i = 0; i < 4; ++i)
#pragma unroll
    for (int g = 0; g < 4; ++g) acc[i][g] = (floatx4){0.f, 0.f, 0.f, 0.f};

  // ---------------- phase 1: x_t @ W_ih^T, K=256 ----------------
  {
    const u16* pa1 = Xhi + (size_t)(rbase + ra1) * 256 + ca1 * 8;
    const u16* pa2 = Xhi + (size_t)(rbase + ra2) * 256 + ca2 * 8;
    const u16* pl1 = Xlo + (size_t)(rbase + ra1) * 256 + ca1 * 8;
    const u16* pl2 = Xlo + (size_t)(rbase + ra2) * 256 + ca2 * 8;
    const u16* pb1 = Bxh + (size_t)(cbase + rb1) * 256 + cb1 * 8;
    const u16* pc1 = Bxl + (size_t)(cbase + rb1) * 256 + cb1 * 8;
    const u16* pb2 = Bxh + (size_t)(cbase + rb2) * 256 + cb2 * 8;
    const u16* pc2 = Bxl + (size_t)(cbase + rb2) * 256 + cb2 * 8;
    for (int kt = 0; kt < 256; kt += 32) {
      glds16(pa1 + kt, &As[0][la1]);
      glds16(pa2 + kt, &As[0][la2]);
      glds16(pl1 + kt, &As[1][la1]);
      glds16(pl2 + kt, &As[1][la2]);
      glds16(pb1 + kt, &Bs[0][lb1]);
      glds16(pc1 + kt, &Bs[1][lb1]);
      if (tid < 128) {
        glds16(pb2 + kt, &Bs[0][lb2]);
        glds16(pc2 + kt, &Bs[1][lb2]);
      }
      __syncthreads();
      bf16x8 ah[4], bh[3], bl[3];
#pragma unroll
      for (int i = 0; i < 4; ++i) ah[i] = *(const bf16x8*)&As[0][aoff + i * 512];
#pragma unroll
      for (int g = 0; g < 3; ++g) bh[g] = *(const bf16x8*)&Bs[0][boff + g * 512];
#pragma unroll
      for (int i = 0; i < 4; ++i)
#pragma unroll
        for (int g = 0; g < 3; ++g)
          acc[i][g] = MFMA16(ah[i], bh[g], acc[i][g]);
#pragma unroll
      for (int g = 0; g < 3; ++g) bl[g] = *(const bf16x8*)&Bs[1][boff + g * 512];
#pragma unroll
      for (int i = 0; i < 4; ++i)
#pragma unroll
        for (int g = 0; g < 3; ++g)
          acc[i][g] = MFMA16(ah[i], bl[g], acc[i][g]);
#pragma unroll
      for (int i = 0; i < 4; ++i) {
        bf16x8 al = *(const bf16x8*)&As[1][aoff + i * 512];
#pragma unroll
        for (int g = 0; g < 3; ++g)
          acc[i][g] = MFMA16(al, bh[g], acc[i][g]);
      }
      __syncthreads();
    }
  }
  // ---------------- phase 2: h @ W_hh^T, K=512; n-group -> acc[.][3] -------
  {
    const u16* pa1 = Shi_in + (size_t)(rbase + ra1) * 512 + ca1 * 8;
    const u16* pa2 = Shi_in + (size_t)(rbase + ra2) * 512 + ca2 * 8;
    const u16* pl1 = Slo_in + (size_t)(rbase + ra1) * 512 + ca1 * 8;
    const u16* pl2 = Slo_in + (size_t)(rbase + ra2) * 512 + ca2 * 8;
    const u16* pb1 = Bhh + (size_t)(cbase + rb1) * 512 + cb1 * 8;
    const u16* pc1 = Bhl + (size_t)(cbase + rb1) * 512 + cb1 * 8;
    const u16* pb2 = Bhh + (size_t)(cbase + rb2) * 512 + cb2 * 8;
    const u16* pc2 = Bhl + (size_t)(cbase + rb2) * 512 + cb2 * 8;
    for (int kt = 0; kt < 512; kt += 32) {
      glds16(pa1 + kt, &As[0][la1]);
      glds16(pa2 + kt, &As[0][la2]);
      glds16(pl1 + kt, &As[1][la1]);
      glds16(pl2 + kt, &As[1][la2]);
      glds16(pb1 + kt, &Bs[0][lb1]);
      glds16(pc1 + kt, &Bs[1][lb1]);
      if (tid < 128) {
        glds16(pb2 + kt, &Bs[0][lb2]);
        glds16(pc2 + kt, &Bs[1][lb2]);
      }
      __syncthreads();
      bf16x8 ah[4], bh[3], bl[3];
#pragma unroll
      for (int i = 0; i < 4; ++i) ah[i] = *(const bf16x8*)&As[0][aoff + i * 512];
#pragma unroll
      for (int g = 0; g < 3; ++g) bh[g] = *(const bf16x8*)&Bs[0][boff + g * 512];
#pragma unroll
      for (int i = 0; i < 4; ++i) {
        acc[i][0] = MFMA16(ah[i], bh[0], acc[i][0]);
        acc[i][1] = MFMA16(ah[i], bh[1], acc[i][1]);
        acc[i][3] = MFMA16(ah[i], bh[2], acc[i][3]);
      }
#pragma unroll
      for (int g = 0; g < 3; ++g) bl[g] = *(const bf16x8*)&Bs[1][boff + g * 512];
#pragma unroll
      for (int i = 0; i < 4; ++i) {
        acc[i][0] = MFMA16(ah[i], bl[0], acc[i][0]);
        acc[i][1] = MFMA16(ah[i], bl[1], acc[i][1]);
        acc[i][3] = MFMA16(ah[i], bl[2], acc[i][3]);
      }
#pragma unroll
      for (int i = 0; i < 4; ++i) {
        bf16x8 al = *(const bf16x8*)&As[1][aoff + i * 512];
        acc[i][0] = MFMA16(al, bh[0], acc[i][0]);
        acc[i][1] = MFMA16(al, bh[1], acc[i][1]);
        acc[i][3] = MFMA16(al, bh[2], acc[i][3]);
      }
      __syncthreads();
    }
  }

  // ---------------- epilogue: GRU gate in registers ----------------
  const int c0g = cbase + wc + lrow;
  const int j = (((bx << 1) | (wave & 1)) << 4) | lrow;
  const float brz0 = bihg[c0g] + bhhg[c0g];
  const float brz1 = bihg[c0g + 16] + bhhg[c0g + 16];
  const float bin = bihg[c0g + 32];
  const float bhn = bhhg[c0g + 32];
#pragma unroll
  for (int i = 0; i < 4; ++i) {
    int r0 = rbase + wr + i * 16 + kq * 4;
#pragma unroll
    for (int rr = 0; rr < 4; ++rr) {
      int row = r0 + rr;
      if (row >= N_NODES) continue;
      float r = sigmoid_f(acc[i][0][rr] + brz0);
      float z = sigmoid_f(acc[i][1][rr] + brz1);
      float nn = tanh_f(acc[i][2][rr] + bin + r * (acc[i][3][rr] + bhn));
      size_t o = (size_t)row * H_DIM + j;
      float hp = bf2f(Shi_in[o]) + bf2f(Slo_in[o]);
      float hv = (1.0f - z) * nn + z * hp;
      u16 hb = f2bf(hv);
      Ghi[o] = hb;
      Glo[o] = f2bf(hv - bf2f(hb));
    }
  }
}

// One conv K-step: 3 sub-phases of 8 MFMA each. (round-7: pipelined conv is
// neutral vs 2-barrier baseline -- kept since it preserves ~6 blocks/CU and
// round-4's "+360us" was a cross-machine artifact.)
__device__ __forceinline__ void conv_kstep(const u16 (&As)[2][2][2048],
                                           const u16 (&Bs)[2][2][4096], int cur,
                                           int aoff, int boff,
                                           floatx4 (&acc)[2][4]) {
  bf16x8 ah[2], bh[4], bl[4], al[2];
#pragma unroll
  for (int i = 0; i < 2; ++i) ah[i] = *(const bf16x8*)&As[cur][0][aoff + i * 512];
#pragma unroll
  for (int jj = 0; jj < 4; ++jj) bh[jj] = *(const bf16x8*)&Bs[cur][0][boff + jj * 512];
  __builtin_amdgcn_s_setprio(1);
#pragma unroll
  for (int i = 0; i < 2; ++i)
#pragma unroll
    for (int jj = 0; jj < 4; ++jj) acc[i][jj] = MFMA16(ah[i], bh[jj], acc[i][jj]);
  __builtin_amdgcn_s_setprio(0);
  __builtin_amdgcn_s_barrier();
#pragma unroll
  for (int jj = 0; jj < 4; ++jj) bl[jj] = *(const bf16x8*)&Bs[cur][1][boff + jj * 512];
  __builtin_amdgcn_s_setprio(1);
#pragma unroll
  for (int i = 0; i < 2; ++i)
#pragma unroll
    for (int jj = 0; jj < 4; ++jj) acc[i][jj] = MFMA16(ah[i], bl[jj], acc[i][jj]);
  __builtin_amdgcn_s_setprio(0);
  __builtin_amdgcn_s_barrier();
#pragma unroll
  for (int i = 0; i < 2; ++i) al[i] = *(const bf16x8*)&As[cur][1][aoff + i * 512];
  __builtin_amdgcn_s_setprio(1);
#pragma unroll
  for (int i = 0; i < 2; ++i)
#pragma unroll
    for (int jj = 0; jj < 4; ++jj) acc[i][jj] = MFMA16(al[i], bh[jj], acc[i][jj]);
  __builtin_amdgcn_s_setprio(0);
  __builtin_amdgcn_s_barrier();
}

// ============ conv GEMM: 64x128 bf16x3, pipelined, fp16 output ==============
__global__ __launch_bounds__(256) void gemm_conv(
    const u16* __restrict__ Ahi, const u16* __restrict__ Alo,
    const u16* __restrict__ Bhi, const u16* __restrict__ Blo,
    _Float16* __restrict__ C, int M, int Nn, int K) {
  __shared__ u16 As[2][2][2048];  // [buf][hi/lo] 64 rows x 32 k
  __shared__ u16 Bs[2][2][4096];  // [buf][hi/lo] 128 rows x 32 k
  const int tid = threadIdx.x;
  const int lane = tid & 63;
  const int wave = tid >> 6;
  // T1: XCD-chunked swizzle; 632 blocks = 8 * 79
  const int bid = blockIdx.y * 4 + blockIdx.x;
  const int lid = (bid & 7) * 79 + (bid >> 3);
  const int bx = lid & 3, by = lid >> 2;
  const int rbase = by * 64;
  const int cbase = bx * 128;

  const int sa = tid;
  const int ra = sa >> 2, ca = (sa & 3) ^ ((ra >> 1) & 3);
  const int la = (sa >> 6) << 9;
  const int sb1 = tid, sb2 = tid + 256;
  const int rb1 = sb1 >> 2, cb1 = (sb1 & 3) ^ ((rb1 >> 1) & 3);
  const int rb2 = sb2 >> 2, cb2 = (sb2 & 3) ^ ((rb2 >> 1) & 3);
  const int lb1 = (sb1 >> 6) << 9, lb2 = (sb2 >> 6) << 9;
  const size_t oA = (size_t)(rbase + ra) * K + ca * 8;
  const size_t oB1 = (size_t)(cbase + rb1) * K + cb1 * 8;
  const size_t oB2 = (size_t)(cbase + rb2) * K + cb2 * 8;

  const int wr = (wave >> 1) * 32;
  const int wc = (wave & 1) * 64;
  const int lrow = lane & 15;
  const int kq = lane >> 4;
  const int swz = kq ^ ((lrow >> 1) & 3);
  const int aoff = (wr + lrow) * 32 + swz * 8;
  const int boff = (wc + lrow) * 32 + swz * 8;

  auto stage = [&](int buf, int t) {  // 6 loads per thread, uniform
    const int kt = t * 32;
    glds16(Ahi + oA + kt, &As[buf][0][la]);
    glds16(Alo + oA + kt, &As[buf][1][la]);
    glds16(Bhi + oB1 + kt, &Bs[buf][0][lb1]);
    glds16(Bhi + oB2 + kt, &Bs[buf][0][lb2]);
    glds16(Blo + oB1 + kt, &Bs[buf][1][lb1]);
    glds16(Blo + oB2 + kt, &Bs[buf][1][lb2]);
  };

  floatx4 acc[2][4];
#pragma unroll
  for (int i = 0; i < 2; ++i)
#pragma unroll
    for (int jj = 0; jj < 4; ++jj) acc[i][jj] = (floatx4){0.f, 0.f, 0.f, 0.f};

  const int NT = K >> 5;  // 16
  stage(0, 0);
  stage(1, 1);
  int cur = 0;
  for (int t = 0; t < NT; ++t) {
    if (t < NT - 1) asm volatile("s_waitcnt vmcnt(6)" ::: "memory");
    else            asm volatile("s_waitcnt vmcnt(0)" ::: "memory");
    __builtin_amdgcn_s_barrier();
    __builtin_amdgcn_sched_barrier(0);
    conv_kstep(As, Bs, cur, aoff, boff, acc);
    __builtin_amdgcn_sched_barrier(0);
    if (t + 2 < NT) stage(cur, t + 2);
    cur ^= 1;
  }

#pragma unroll
  for (int jj = 0; jj < 4; ++jj) {
    int col = cbase + wc + jj * 16 + lrow;
#pragma unroll
    for (int i = 0; i < 2; ++i) {
      int r0 = rbase + wr + i * 16 + kq * 4;
#pragma unroll
      for (int rr = 0; rr < 4; ++rr) {
        int row = r0 + rr;
        if (row < M) C[(size_t)row * Nn + col] = (_Float16)acc[i][jj][rr];
      }
    }
  }
}

// ---------------- split / preprocessing kernels ----------------
__global__ void split_grouped(const float* __restrict__ W, u16* __restrict__ hi,
                              u16* __restrict__ lo, int K) {
  int i = blockIdx.x * 256 + threadIdx.x;
  if (i >= H3 * K) return;
  int r3h = i / K, k = i - r3h * K;
  int g = r3h >> 9, j = r3h & 511;
  int nr = ((j >> 4) * 48) + (g << 4) + (j & 15);
  float v = W[i];
  u16 h = f2bf(v);
  size_t o = (size_t)nr * K + k;
  hi[o] = h;
  lo[o] = f2bf(v - bf2f(h));
}

__global__ void bias_grouped(const float* __restrict__ bih, const float* __restrict__ bhh,
                             float* __restrict__ bihg, float* __restrict__ bhhg) {
  int n = blockIdx.x * 256 + threadIdx.x;
  if (n >= H3) return;
  int g = n >> 9, j = n & 511;
  int nr = ((j >> 4) * 48) + (g << 4) + (j & 15);
  bihg[nr] = bih[n];
  bhhg[nr] = bhh[n];
}

__global__ void split_convw(const float* __restrict__ W, u16* __restrict__ hi,
                            u16* __restrict__ lo) {
  int o = blockIdx.x * 256 + threadIdx.x;
  if (o >= NUM_CONVS * H_DIM * H_DIM) return;
  int k = o & 511, j = (o >> 9) & 511, l = o >> 18;
  float v = W[(size_t)l * H_DIM * H_DIM + (size_t)k * H_DIM + j];
  u16 h = f2bf(v);
  hi[o] = h;
  lo[o] = f2bf(v - bf2f(h));
}

__global__ void split_xs(const float* __restrict__ xs, u16* __restrict__ hi,
                         u16* __restrict__ lo) {
  const int QP = MP * D_IN / 4;
  int q = blockIdx.x * 256 + threadIdx.x;
  if (q >= T_STEPS * QP) return;
  int t = q / QP;
  int rem = (q - t * QP) * 4;
  size_t o = (size_t)t * MP * D_IN + rem;
  uint2 hp = make_uint2(0u, 0u), lp = make_uint2(0u, 0u);
  if (rem < N_NODES * D_IN) {
    float4 v = *(const float4*)(xs + (size_t)t * N_NODES * D_IN + rem);
    float vv[4] = {v.x, v.y, v.z, v.w};
    u16 hb[4], lb[4];
#pragma unroll
    for (int k = 0; k < 4; ++k) {
      hb[k] = f2bf(vv[k]);
      lb[k] = f2bf(vv[k] - bf2f(hb[k]));
    }
    hp.x = (u32)hb[0] | ((u32)hb[1] << 16);
    hp.y = (u32)hb[2] | ((u32)hb[3] << 16);
    lp.x = (u32)lb[0] | ((u32)lb[1] << 16);
    lp.y = (u32)lb[2] | ((u32)lb[3] << 16);
  }
  *(uint2*)(hi + o) = hp;
  *(uint2*)(lo + o) = lp;
}

__global__ void deg_kernel(const int* __restrict__ col, const float* __restrict__ w,
                           float* __restrict__ deg, int* __restrict__ counts) {
  int e = blockIdx.x * blockDim.x + threadIdx.x;
  if (e >= E_EDGES) return;
  int c = col[e];
  atomicAdd(&deg[c], w[e]);
  atomicAdd(&counts[c], 1);
}

__global__ void dinv_kernel(float* __restrict__ deg_dinv, float* __restrict__ selfw) {
  int n = blockIdx.x * blockDim.x + threadIdx.x;
  if (n >= N_NODES) return;
  float d = deg_dinv[n] + 1.0f;
  float di = 1.0f / sqrtf(d);
  deg_dinv[n] = di;
  selfw[n] = 1.0f / d;
}

__global__ __launch_bounds__(1024) void scan_kernel(const int* __restrict__ counts,
                                                    int* __restrict__ offsets, int n) {
  __shared__ int smem[1024];
  __shared__ int carry_s;
  if (threadIdx.x == 0) carry_s = 0;
  __syncthreads();
  for (int base = 0; base < n; base += 1024) {
    int i = base + threadIdx.x;
    int v = (i < n) ? counts[i] : 0;
    smem[threadIdx.x] = v;
    __syncthreads();
    for (int off = 1; off < 1024; off <<= 1) {
      int t = (threadIdx.x >= off) ? smem[threadIdx.x - off] : 0;
      __syncthreads();
      smem[threadIdx.x] += t;
      __syncthreads();
    }
    if (i < n) offsets[i] = carry_s + smem[threadIdx.x] - v;
    int total = smem[1023];
    __syncthreads();
    if (threadIdx.x == 0) carry_s += total;
    __syncthreads();
  }
  if (threadIdx.x == 0) offsets[n] = carry_s;
}

__global__ void scatter_kernel(const int* __restrict__ row, const int* __restrict__ col,
                               const float* __restrict__ w, const float* __restrict__ dinv,
                               const int* __restrict__ offsets, int* __restrict__ cursor,
                               int* __restrict__ csr_row, float* __restrict__ csr_norm) {
  int e = blockIdx.x * blockDim.x + threadIdx.x;
  if (e >= E_EDGES) return;
  int r = row[e], c = col[e];
  float nrm = dinv[r] * w[e] * dinv[c];
  int pos = offsets[c] + atomicAdd(&cursor[c], 1);
  csr_row[pos] = r;
  csr_norm[pos] = nrm;
}

// ---------------- GCN aggregation (fp16 hW) + relu + split (+ final lin) ---
// Round-8 change: fp64 -> fp32 accumulation. Sums of ~16 terms |w*x|<~0.25 ->
// fp32 accum error ~7e-7 << 4.88e-4 absmax (fp16-hW-quantization dominated).
// Halves VALU cost and frees 16 VGPRs -> more resident waves for the
// latency-bound edge gather.
__device__ __forceinline__ void fma8h(float* a, float w, const _Float16* p) {
  f16x4 x = *(const f16x4*)p;
  f16x4 y = *(const f16x4*)(p + 256);
  a[0] = fmaf(w, (float)x[0], a[0]);
  a[1] = fmaf(w, (float)x[1], a[1]);
  a[2] = fmaf(w, (float)x[2], a[2]);
  a[3] = fmaf(w, (float)x[3], a[3]);
  a[4] = fmaf(w, (float)y[0], a[4]);
  a[5] = fmaf(w, (float)y[1], a[5]);
  a[6] = fmaf(w, (float)y[2], a[6]);
  a[7] = fmaf(w, (float)y[3], a[7]);
}

template <bool FINAL>
__global__ __launch_bounds__(256) void agg_kernel(
    const _Float16* __restrict__ hW, const int* __restrict__ csr_row,
    const float* __restrict__ csr_norm, const int* __restrict__ offsets,
    const float* __restrict__ selfw, const float* __restrict__ bias,
    u16* __restrict__ Shi, u16* __restrict__ Slo,
    const float* __restrict__ lw, const float* __restrict__ lb,
    float* __restrict__ out) {
  const int n = (blockIdx.x << 2) | (threadIdx.x >> 6);
  const int lane = threadIdx.x & 63;
  if (n >= N_NODES) return;
  const int c0 = lane << 2;
  const int beg = offsets[n], end = offsets[n + 1];
  float a0[8] = {}, a1[8] = {};
  int j = beg;
  for (; j + 4 <= end; j += 4) {
    int r0 = csr_row[j], r1 = csr_row[j + 1], r2 = csr_row[j + 2], r3 = csr_row[j + 3];
    float w0 = csr_norm[j], w1 = csr_norm[j + 1], w2 = csr_norm[j + 2], w3 = csr_norm[j + 3];
    fma8h(a0, w0, hW + (size_t)r0 * H_DIM + c0);
    fma8h(a1, w1, hW + (size_t)r1 * H_DIM + c0);
    fma8h(a0, w2, hW + (size_t)r2 * H_DIM + c0);
    fma8h(a1, w3, hW + (size_t)r3 * H_DIM + c0);
  }
  for (; j < end; ++j) fma8h(a0, csr_norm[j], hW + (size_t)csr_row[j] * H_DIM + c0);

  const float sw = selfw[n];
  const _Float16* ps = hW + (size_t)n * H_DIM + c0;
  f16x4 sa = *(const f16x4*)ps;
  f16x4 sb = *(const f16x4*)(ps + 256);
  float4 ba = *(const float4*)(bias + c0);
  float4 bb = *(const float4*)(bias + 256 + c0);
  float v[8];
  v[0] = fmaxf(fmaf(sw, (float)sa[0], a0[0] + a1[0]) + ba.x, 0.f);
  v[1] = fmaxf(fmaf(sw, (float)sa[1], a0[1] + a1[1]) + ba.y, 0.f);
  v[2] = fmaxf(fmaf(sw, (float)sa[2], a0[2] + a1[2]) + ba.z, 0.f);
  v[3] = fmaxf(fmaf(sw, (float)sa[3], a0[3] + a1[3]) + ba.w, 0.f);
  v[4] = fmaxf(fmaf(sw, (float)sb[0], a0[4] + a1[4]) + bb.x, 0.f);
  v[5] = fmaxf(fmaf(sw, (float)sb[1], a0[5] + a1[5]) + bb.y, 0.f);
  v[6] = fmaxf(fmaf(sw, (float)sb[2], a0[6] + a1[6]) + bb.z, 0.f);
  v[7] = fmaxf(fmaf(sw, (float)sb[3], a0[7] + a1[7]) + bb.w, 0.f);

  size_t o = (size_t)n * H_DIM + c0;
  u16 hb[8], lb2[8];
#pragma unroll
  for (int k = 0; k < 8; ++k) {
    hb[k] = f2bf(v[k]);
    lb2[k] = f2bf(v[k] - bf2f(hb[k]));
  }
  uint2 p;
  p.x = (u32)hb[0] | ((u32)hb[1] << 16);
  p.y = (u32)hb[2] | ((u32)hb[3] << 16);
  *(uint2*)(Shi + o) = p;
  p.x = (u32)hb[4] | ((u32)hb[5] << 16);
  p.y = (u32)hb[6] | ((u32)hb[7] << 16);
  *(uint2*)(Shi + o + 256) = p;
  p.x = (u32)lb2[0] | ((u32)lb2[1] << 16);
  p.y = (u32)lb2[2] | ((u32)lb2[3] << 16);
  *(uint2*)(Slo + o) = p;
  p.x = (u32)lb2[4] | ((u32)lb2[5] << 16);
  p.y = (u32)lb2[6] | ((u32)lb2[7] << 16);
  *(uint2*)(Slo + o + 256) = p;

  if (FINAL) {
    float4 la = *(const float4*)(lw + c0);
    float4 lbv = *(const float4*)(lw + 256 + c0);
    float s = v[0] * la.x + v[1] * la.y + v[2] * la.z + v[3] * la.w +
              v[4] * lbv.x + v[5] * lbv.y + v[6] * lbv.z + v[7] * lbv.w;
#pragma unroll
    for (int off2 = 32; off2 > 0; off2 >>= 1) s += __shfl_down(s, off2, 64);
    if (lane == 0) out[n] = s + lb[0];
  }
}

// ---------------- launch ----------------
extern "C" void kernel_launch(void* const* d_in, const int* in_sizes, int n_in,
                              void* d_out, int out_size, void* d_ws, size_t ws_size,
                              hipStream_t stream) {
  const float* xs = (const float*)d_in[0];
  const int* ei = (const int*)d_in[1];
  const float* ew = (const float*)d_in[2];
  const float* W_ih = (const float*)d_in[3];
  const float* W_hh = (const float*)d_in[4];
  const float* b_ih = (const float*)d_in[5];
  const float* b_hh = (const float*)d_in[6];
  const float* conv_W = (const float*)d_in[7];
  const float* conv_b = (const float*)d_in[8];
  const float* lin_W = (const float*)d_in[9];
  const float* lin_b = (const float*)d_in[10];
  float* out = (float*)d_out;

  const int* row = ei;
  const int* col = ei + E_EDGES;

  char* ws = (char*)d_ws;
  size_t off = 0;
  auto alloc = [&](size_t bytes) -> void* {
    void* p = ws + off;
    off += (bytes + 255) & ~(size_t)255;
    return p;
  };
  u16* S_hi = (u16*)alloc((size_t)MP * H_DIM * 2);  // h state splits
  u16* S_lo = (u16*)alloc((size_t)MP * H_DIM * 2);
  u16* G_hi = (u16*)alloc((size_t)MP * H_DIM * 2);  // gate / agg0 out
  u16* G_lo = (u16*)alloc((size_t)MP * H_DIM * 2);
  _Float16* hW16 = (_Float16*)alloc((size_t)MP * H_DIM * 2);
  u16* xs_hi = (u16*)alloc((size_t)T_STEPS * MP * D_IN * 2);
  u16* xs_lo = (u16*)alloc((size_t)T_STEPS * MP * D_IN * 2);
  u16* WihG_hi = (u16*)alloc((size_t)H3 * D_IN * 2);
  u16* WihG_lo = (u16*)alloc((size_t)H3 * D_IN * 2);
  u16* WhhG_hi = (u16*)alloc((size_t)H3 * H_DIM * 2);
  u16* WhhG_lo = (u16*)alloc((size_t)H3 * H_DIM * 2);
  u16* Wc_hi = (u16*)alloc((size_t)NUM_CONVS * H_DIM * H_DIM * 2);
  u16* Wc_lo = (u16*)alloc((size_t)NUM_CONVS * H_DIM * H_DIM * 2);
  float* bihg = (float*)alloc(H3 * 4);
  float* bhhg = (float*)alloc(H3 * 4);
  float* dinv = (float*)alloc(N_NODES * 4);
  float* selfw = (float*)alloc(N_NODES * 4);
  float* csr_norm = (float*)alloc(E_EDGES * 4);
  int* csr_row = (int*)alloc(E_EDGES * 4);
  int* offsets = (int*)alloc((N_NODES + 1) * 4);
  int* counts = (int*)alloc(N_NODES * 4);
  int* cursor = (int*)alloc(N_NODES * 4);

  hipMemsetAsync(S_hi, 0, (size_t)MP * H_DIM * 2, stream);
  hipMemsetAsync(S_lo, 0, (size_t)MP * H_DIM * 2, stream);
  hipMemsetAsync(G_hi, 0, (size_t)MP * H_DIM * 2, stream);
  hipMemsetAsync(G_lo, 0, (size_t)MP * H_DIM * 2, stream);
  hipMemsetAsync(hW16, 0, (size_t)MP * H_DIM * 2, stream);
  hipMemsetAsync(dinv, 0, N_NODES * 4, stream);
  hipMemsetAsync(counts, 0, N_NODES * 4, stream);
  hipMemsetAsync(cursor, 0, N_NODES * 4, stream);

  // one-time preprocessing
  deg_kernel<<<(E_EDGES + 255) / 256, 256, 0, stream>>>(col, ew, dinv, counts);
  dinv_kernel<<<(N_NODES + 255) / 256, 256, 0, stream>>>(dinv, selfw);
  scan_kernel<<<1, 1024, 0, stream>>>(counts, offsets, N_NODES);
  scatter_kernel<<<(E_EDGES + 255) / 256, 256, 0, stream>>>(row, col, ew, dinv, offsets,
                                                            cursor, csr_row, csr_norm);
  split_grouped<<<(H3 * D_IN + 255) / 256, 256, 0, stream>>>(W_ih, WihG_hi, WihG_lo, D_IN);
  split_grouped<<<(H3 * H_DIM + 255) / 256, 256, 0, stream>>>(W_hh, WhhG_hi, WhhG_lo, H_DIM);
  bias_grouped<<<(H3 + 255) / 256, 256, 0, stream>>>(b_ih, b_hh, bihg, bhhg);
  split_convw<<<(NUM_CONVS * H_DIM * H_DIM + 255) / 256, 256, 0, stream>>>(conv_W, Wc_hi, Wc_lo);
  split_xs<<<(T_STEPS * MP * D_IN / 4 + 255) / 256, 256, 0, stream>>>(xs, xs_hi, xs_lo);

  dim3 blk(256);
  dim3 g_gru(16, MP / 128);       // 2 jb per block x 79 row-blocks
  dim3 g_conv(H_DIM / 128, MP / 64);  // 4 x 158 = 632 blocks
  int g_agg = (N_NODES + 3) / 4;

  for (int t = 0; t < T_STEPS; ++t) {
    // fused: gi + gh GEMMs + GRU gate -> G splits
    gru_fused<<<g_gru, blk, 0, stream>>>(
        xs_hi + (size_t)t * MP * D_IN, xs_lo + (size_t)t * MP * D_IN,
        S_hi, S_lo, WihG_hi, WihG_lo, WhhG_hi, WhhG_lo, bihg, bhhg, G_hi, G_lo);
    // conv0: hW16 = G @ Wc0 ; agg0 -> G
    gemm_conv<<<g_conv, blk, 0, stream>>>(G_hi, G_lo, Wc_hi, Wc_lo, hW16,
                                          N_NODES, H_DIM, H_DIM);
    agg_kernel<false><<<g_agg, 256, 0, stream>>>(
        hW16, csr_row, csr_norm, offsets, selfw, conv_b, G_hi, G_lo,
        nullptr, nullptr, nullptr);
    // conv1: hW16 = G @ Wc1 ; agg1(final) -> S state + fused linear
    gemm_conv<<<g_conv, blk, 0, stream>>>(
        G_hi, G_lo, Wc_hi + (size_t)H_DIM * H_DIM, Wc_lo + (size_t)H_DIM * H_DIM, hW16,
        N_NODES, H_DIM, H_DIM);
    agg_kernel<true><<<g_agg, 256, 0, stream>>>(
        hW16, csr_row, csr_norm, offsets, selfw, conv_b + H_DIM, S_hi, S_lo,
        lin_W, lin_b, out + (size_t)t * N_NODES);
  }
}

// Round 9
// 2196.520 us; speedup vs baseline: 1.1591x; 1.1110x over previous
//
#include <hip/hip_runtime.h>
#include <math.h>

#define T_STEPS 12
#define N_NODES 10000
#define MP 10112  // 79*128, padded M
#define D_IN 256
#define H_DIM 512
#define H3 1536
#define E_EDGES 160000
#define NUM_CONVS 2

typedef __bf16 bf16x8 __attribute__((ext_vector_type(8)));
typedef _Float16 f16x8 __attribute__((ext_vector_type(8)));
typedef float floatx4 __attribute__((ext_vector_type(4)));
typedef _Float16 f16x4 __attribute__((ext_vector_type(4)));
typedef unsigned short u16;
typedef unsigned int u32;

__device__ __forceinline__ u16 f2bf(float f) {
  unsigned int u = __float_as_uint(f);
  u += 0x7FFFu + ((u >> 16) & 1u);  // round-nearest-even (no NaN inputs)
  return (u16)(u >> 16);
}
__device__ __forceinline__ float bf2f(u16 s) {
  return __uint_as_float(((unsigned int)s) << 16);
}
__device__ __forceinline__ float sigmoid_f(float x) {
  return __builtin_amdgcn_rcpf(1.0f + __expf(-x));
}
__device__ __forceinline__ float tanh_f(float x) {
  return 1.0f - 2.0f * __builtin_amdgcn_rcpf(1.0f + __expf(2.0f * x));
}

__device__ __forceinline__ void glds16(const void* g, void* l) {
  __builtin_amdgcn_global_load_lds(
      (const __attribute__((address_space(1))) unsigned int*)g,
      (__attribute__((address_space(3))) unsigned int*)l, 16, 0, 0);
}

#define MFMA16(a, b, c) __builtin_amdgcn_mfma_f32_16x16x32_bf16((a), (b), (c), 0, 0, 0)
#define MFMA16H(a, b, c) __builtin_amdgcn_mfma_f32_16x16x32_f16((a), (b), (c), 0, 0, 0)

// ============ fused GRU: verified 2-barrier structure + XCD swizzle =========
// (round-7 verified: 85 us/dispatch, MfmaUtil 33%, FETCH 60MB = traffic floor,
// 837 TF = ~93% of the m97-structure ceiling. Round-4 lesson: LDS dbuf halves
// residency -> net loss. bf16x3 kept here: recurrent state precision.)
// Round-9: epilogue writes single fp16 G16 (conv consumes fp16 directly).
__global__ __launch_bounds__(256) void gru_fused(
    const u16* __restrict__ Xhi, const u16* __restrict__ Xlo,      // (MP,256)
    const u16* __restrict__ Shi_in, const u16* __restrict__ Slo_in,// (MP,512)
    const u16* __restrict__ Bxh, const u16* __restrict__ Bxl,      // WihG (1536,256)
    const u16* __restrict__ Bhh, const u16* __restrict__ Bhl,      // WhhG (1536,512)
    const float* __restrict__ bihg, const float* __restrict__ bhhg,
    _Float16* __restrict__ G16) {
  __shared__ u16 As[2][4096];  // 128 rows x 32 k, hi/lo, swizzled 16B slots
  __shared__ u16 Bs[2][3072];  // 96 rows x 32 k
  const int tid = threadIdx.x;
  const int lane = tid & 63;
  const int wave = tid >> 6;
  // T1: XCD-chunked swizzle; 1264 blocks = 8 * 158 (exactly divisible)
  const int bid = blockIdx.y * 16 + blockIdx.x;
  const int lid = (bid & 7) * 158 + (bid >> 3);
  const int bx = lid & 15, by = lid >> 4;
  const int rbase = by * 128;
  const int cbase = bx * 96;

  // slot decompositions (K-independent)
  const int sa1 = tid, sa2 = tid + 256;
  const int ra1 = sa1 >> 2, ca1 = (sa1 & 3) ^ ((ra1 >> 1) & 3);
  const int ra2 = sa2 >> 2, ca2 = (sa2 & 3) ^ ((ra2 >> 1) & 3);
  const int la1 = (sa1 >> 6) << 9;
  const int la2 = (sa2 >> 6) << 9;
  const int sb1 = tid;
  const int rb1 = sb1 >> 2, cb1 = (sb1 & 3) ^ ((rb1 >> 1) & 3);
  const int lb1 = (sb1 >> 6) << 9;
  const int sb2 = 256 + tid;
  const int rb2 = sb2 >> 2, cb2 = (sb2 & 3) ^ ((rb2 >> 1) & 3);
  const int lb2 = (sb2 >> 6) << 9;

  const int wr = (wave >> 1) * 64;
  const int wc = (wave & 1) * 48;
  const int lrow = lane & 15;
  const int kq = lane >> 4;
  const int swz = kq ^ ((lrow >> 1) & 3);
  const int aoff = (wr + lrow) * 32 + swz * 8;
  const int boff = (wc + lrow) * 32 + swz * 8;

  floatx4 acc[4][4];  // [row-frag][gate: 0=r 1=z 2=ni 3=nh]
#pragma unroll
  for (int i = 0; i < 4; ++i)
#pragma unroll
    for (int g = 0; g < 4; ++g) acc[i][g] = (floatx4){0.f, 0.f, 0.f, 0.f};

  // ---------------- phase 1: x_t @ W_ih^T, K=256 ----------------
  {
    const u16* pa1 = Xhi + (size_t)(rbase + ra1) * 256 + ca1 * 8;
    const u16* pa2 = Xhi + (size_t)(rbase + ra2) * 256 + ca2 * 8;
    const u16* pl1 = Xlo + (size_t)(rbase + ra1) * 256 + ca1 * 8;
    const u16* pl2 = Xlo + (size_t)(rbase + ra2) * 256 + ca2 * 8;
    const u16* pb1 = Bxh + (size_t)(cbase + rb1) * 256 + cb1 * 8;
    const u16* pc1 = Bxl + (size_t)(cbase + rb1) * 256 + cb1 * 8;
    const u16* pb2 = Bxh + (size_t)(cbase + rb2) * 256 + cb2 * 8;
    const u16* pc2 = Bxl + (size_t)(cbase + rb2) * 256 + cb2 * 8;
    for (int kt = 0; kt < 256; kt += 32) {
      glds16(pa1 + kt, &As[0][la1]);
      glds16(pa2 + kt, &As[0][la2]);
      glds16(pl1 + kt, &As[1][la1]);
      glds16(pl2 + kt, &As[1][la2]);
      glds16(pb1 + kt, &Bs[0][lb1]);
      glds16(pc1 + kt, &Bs[1][lb1]);
      if (tid < 128) {
        glds16(pb2 + kt, &Bs[0][lb2]);
        glds16(pc2 + kt, &Bs[1][lb2]);
      }
      __syncthreads();
      bf16x8 ah[4], bh[3], bl[3];
#pragma unroll
      for (int i = 0; i < 4; ++i) ah[i] = *(const bf16x8*)&As[0][aoff + i * 512];
#pragma unroll
      for (int g = 0; g < 3; ++g) bh[g] = *(const bf16x8*)&Bs[0][boff + g * 512];
#pragma unroll
      for (int i = 0; i < 4; ++i)
#pragma unroll
        for (int g = 0; g < 3; ++g)
          acc[i][g] = MFMA16(ah[i], bh[g], acc[i][g]);
#pragma unroll
      for (int g = 0; g < 3; ++g) bl[g] = *(const bf16x8*)&Bs[1][boff + g * 512];
#pragma unroll
      for (int i = 0; i < 4; ++i)
#pragma unroll
        for (int g = 0; g < 3; ++g)
          acc[i][g] = MFMA16(ah[i], bl[g], acc[i][g]);
#pragma unroll
      for (int i = 0; i < 4; ++i) {
        bf16x8 al = *(const bf16x8*)&As[1][aoff + i * 512];
#pragma unroll
        for (int g = 0; g < 3; ++g)
          acc[i][g] = MFMA16(al, bh[g], acc[i][g]);
      }
      __syncthreads();
    }
  }
  // ---------------- phase 2: h @ W_hh^T, K=512; n-group -> acc[.][3] -------
  {
    const u16* pa1 = Shi_in + (size_t)(rbase + ra1) * 512 + ca1 * 8;
    const u16* pa2 = Shi_in + (size_t)(rbase + ra2) * 512 + ca2 * 8;
    const u16* pl1 = Slo_in + (size_t)(rbase + ra1) * 512 + ca1 * 8;
    const u16* pl2 = Slo_in + (size_t)(rbase + ra2) * 512 + ca2 * 8;
    const u16* pb1 = Bhh + (size_t)(cbase + rb1) * 512 + cb1 * 8;
    const u16* pc1 = Bhl + (size_t)(cbase + rb1) * 512 + cb1 * 8;
    const u16* pb2 = Bhh + (size_t)(cbase + rb2) * 512 + cb2 * 8;
    const u16* pc2 = Bhl + (size_t)(cbase + rb2) * 512 + cb2 * 8;
    for (int kt = 0; kt < 512; kt += 32) {
      glds16(pa1 + kt, &As[0][la1]);
      glds16(pa2 + kt, &As[0][la2]);
      glds16(pl1 + kt, &As[1][la1]);
      glds16(pl2 + kt, &As[1][la2]);
      glds16(pb1 + kt, &Bs[0][lb1]);
      glds16(pc1 + kt, &Bs[1][lb1]);
      if (tid < 128) {
        glds16(pb2 + kt, &Bs[0][lb2]);
        glds16(pc2 + kt, &Bs[1][lb2]);
      }
      __syncthreads();
      bf16x8 ah[4], bh[3], bl[3];
#pragma unroll
      for (int i = 0; i < 4; ++i) ah[i] = *(const bf16x8*)&As[0][aoff + i * 512];
#pragma unroll
      for (int g = 0; g < 3; ++g) bh[g] = *(const bf16x8*)&Bs[0][boff + g * 512];
#pragma unroll
      for (int i = 0; i < 4; ++i) {
        acc[i][0] = MFMA16(ah[i], bh[0], acc[i][0]);
        acc[i][1] = MFMA16(ah[i], bh[1], acc[i][1]);
        acc[i][3] = MFMA16(ah[i], bh[2], acc[i][3]);
      }
#pragma unroll
      for (int g = 0; g < 3; ++g) bl[g] = *(const bf16x8*)&Bs[1][boff + g * 512];
#pragma unroll
      for (int i = 0; i < 4; ++i) {
        acc[i][0] = MFMA16(ah[i], bl[0], acc[i][0]);
        acc[i][1] = MFMA16(ah[i], bl[1], acc[i][1]);
        acc[i][3] = MFMA16(ah[i], bl[2], acc[i][3]);
      }
#pragma unroll
      for (int i = 0; i < 4; ++i) {
        bf16x8 al = *(const bf16x8*)&As[1][aoff + i * 512];
        acc[i][0] = MFMA16(al, bh[0], acc[i][0]);
        acc[i][1] = MFMA16(al, bh[1], acc[i][1]);
        acc[i][3] = MFMA16(al, bh[2], acc[i][3]);
      }
      __syncthreads();
    }
  }

  // ---------------- epilogue: GRU gate in registers ----------------
  const int c0g = cbase + wc + lrow;
  const int j = (((bx << 1) | (wave & 1)) << 4) | lrow;
  const float brz0 = bihg[c0g] + bhhg[c0g];
  const float brz1 = bihg[c0g + 16] + bhhg[c0g + 16];
  const float bin = bihg[c0g + 32];
  const float bhn = bhhg[c0g + 32];
#pragma unroll
  for (int i = 0; i < 4; ++i) {
    int r0 = rbase + wr + i * 16 + kq * 4;
#pragma unroll
    for (int rr = 0; rr < 4; ++rr) {
      int row = r0 + rr;
      if (row >= N_NODES) continue;
      float r = sigmoid_f(acc[i][0][rr] + brz0);
      float z = sigmoid_f(acc[i][1][rr] + brz1);
      float nn = tanh_f(acc[i][2][rr] + bin + r * (acc[i][3][rr] + bhn));
      size_t o = (size_t)row * H_DIM + j;
      float hp = bf2f(Shi_in[o]) + bf2f(Slo_in[o]);
      float hv = (1.0f - z) * nn + z * hp;
      G16[o] = (_Float16)hv;
    }
  }
}

// ============ conv GEMM: 64x128 fp16 single-product, pipelined ==============
// Round-9: bf16x3 -> fp16 (1 MFMA per fragment, 3 staging loads/thread,
// LDS 48->24 KB -> 6 blocks/CU). Pipeline always consumes fp16-quantized
// outputs (hW16), so fp16 inputs add ~2.4e-4 RMS -- same order as existing
// fp16-hW error. Recurrent state (S) stays bf16-split; gru stays bf16x3.
__global__ __launch_bounds__(256) void gemm_conv(
    const u16* __restrict__ A16, const u16* __restrict__ B16,
    _Float16* __restrict__ C, int M, int Nn, int K) {
  __shared__ u16 As[2][2048];  // [buf] 64 rows x 32 k fp16
  __shared__ u16 Bs[2][4096];  // [buf] 128 rows x 32 k fp16
  const int tid = threadIdx.x;
  const int lane = tid & 63;
  const int wave = tid >> 6;
  // T1: XCD-chunked swizzle; 632 blocks = 8 * 79
  const int bid = blockIdx.y * 4 + blockIdx.x;
  const int lid = (bid & 7) * 79 + (bid >> 3);
  const int bx = lid & 3, by = lid >> 2;
  const int rbase = by * 64;
  const int cbase = bx * 128;

  const int sa = tid;
  const int ra = sa >> 2, ca = (sa & 3) ^ ((ra >> 1) & 3);
  const int la = (sa >> 6) << 9;
  const int sb1 = tid, sb2 = tid + 256;
  const int rb1 = sb1 >> 2, cb1 = (sb1 & 3) ^ ((rb1 >> 1) & 3);
  const int rb2 = sb2 >> 2, cb2 = (sb2 & 3) ^ ((rb2 >> 1) & 3);
  const int lb1 = (sb1 >> 6) << 9, lb2 = (sb2 >> 6) << 9;
  const size_t oA = (size_t)(rbase + ra) * K + ca * 8;
  const size_t oB1 = (size_t)(cbase + rb1) * K + cb1 * 8;
  const size_t oB2 = (size_t)(cbase + rb2) * K + cb2 * 8;

  const int wr = (wave >> 1) * 32;
  const int wc = (wave & 1) * 64;
  const int lrow = lane & 15;
  const int kq = lane >> 4;
  const int swz = kq ^ ((lrow >> 1) & 3);
  const int aoff = (wr + lrow) * 32 + swz * 8;
  const int boff = (wc + lrow) * 32 + swz * 8;

  auto stage = [&](int buf, int t) {  // 3 loads per thread, uniform
    const int kt = t * 32;
    glds16(A16 + oA + kt, &As[buf][la]);
    glds16(B16 + oB1 + kt, &Bs[buf][lb1]);
    glds16(B16 + oB2 + kt, &Bs[buf][lb2]);
  };

  floatx4 acc[2][4];
#pragma unroll
  for (int i = 0; i < 2; ++i)
#pragma unroll
    for (int jj = 0; jj < 4; ++jj) acc[i][jj] = (floatx4){0.f, 0.f, 0.f, 0.f};

  const int NT = K >> 5;  // 16
  stage(0, 0);
  stage(1, 1);
  int cur = 0;
  for (int t = 0; t < NT; ++t) {
    if (t < NT - 1) asm volatile("s_waitcnt vmcnt(3)" ::: "memory");
    else            asm volatile("s_waitcnt vmcnt(0)" ::: "memory");
    __builtin_amdgcn_s_barrier();
    __builtin_amdgcn_sched_barrier(0);
    {
      f16x8 ah[2], bh[4];
#pragma unroll
      for (int i = 0; i < 2; ++i) ah[i] = *(const f16x8*)&As[cur][aoff + i * 512];
#pragma unroll
      for (int jj = 0; jj < 4; ++jj) bh[jj] = *(const f16x8*)&Bs[cur][boff + jj * 512];
      __builtin_amdgcn_s_setprio(1);
#pragma unroll
      for (int i = 0; i < 2; ++i)
#pragma unroll
        for (int jj = 0; jj < 4; ++jj) acc[i][jj] = MFMA16H(ah[i], bh[jj], acc[i][jj]);
      __builtin_amdgcn_s_setprio(0);
      __builtin_amdgcn_s_barrier();  // reads retired before re-staging buf
    }
    __builtin_amdgcn_sched_barrier(0);
    if (t + 2 < NT) stage(cur, t + 2);
    cur ^= 1;
  }

#pragma unroll
  for (int jj = 0; jj < 4; ++jj) {
    int col = cbase + wc + jj * 16 + lrow;
#pragma unroll
    for (int i = 0; i < 2; ++i) {
      int r0 = rbase + wr + i * 16 + kq * 4;
#pragma unroll
      for (int rr = 0; rr < 4; ++rr) {
        int row = r0 + rr;
        if (row < M) C[(size_t)row * Nn + col] = (_Float16)acc[i][jj][rr];
      }
    }
  }
}

// ---------------- split / preprocessing kernels ----------------
__global__ void split_grouped(const float* __restrict__ W, u16* __restrict__ hi,
                              u16* __restrict__ lo, int K) {
  int i = blockIdx.x * 256 + threadIdx.x;
  if (i >= H3 * K) return;
  int r3h = i / K, k = i - r3h * K;
  int g = r3h >> 9, j = r3h & 511;
  int nr = ((j >> 4) * 48) + (g << 4) + (j & 15);
  float v = W[i];
  u16 h = f2bf(v);
  size_t o = (size_t)nr * K + k;
  hi[o] = h;
  lo[o] = f2bf(v - bf2f(h));
}

__global__ void bias_grouped(const float* __restrict__ bih, const float* __restrict__ bhh,
                             float* __restrict__ bihg, float* __restrict__ bhhg) {
  int n = blockIdx.x * 256 + threadIdx.x;
  if (n >= H3) return;
  int g = n >> 9, j = n & 511;
  int nr = ((j >> 4) * 48) + (g << 4) + (j & 15);
  bihg[nr] = bih[n];
  bhhg[nr] = bhh[n];
}

// conv_W[l][k][j] -> transposed fp16 [l][j][k]
__global__ void split_convw(const float* __restrict__ W, _Float16* __restrict__ w16) {
  int o = blockIdx.x * 256 + threadIdx.x;
  if (o >= NUM_CONVS * H_DIM * H_DIM) return;
  int k = o & 511, j = (o >> 9) & 511, l = o >> 18;
  float v = W[(size_t)l * H_DIM * H_DIM + (size_t)k * H_DIM + j];
  w16[o] = (_Float16)v;
}

__global__ void split_xs(const float* __restrict__ xs, u16* __restrict__ hi,
                         u16* __restrict__ lo) {
  const int QP = MP * D_IN / 4;
  int q = blockIdx.x * 256 + threadIdx.x;
  if (q >= T_STEPS * QP) return;
  int t = q / QP;
  int rem = (q - t * QP) * 4;
  size_t o = (size_t)t * MP * D_IN + rem;
  uint2 hp = make_uint2(0u, 0u), lp = make_uint2(0u, 0u);
  if (rem < N_NODES * D_IN) {
    float4 v = *(const float4*)(xs + (size_t)t * N_NODES * D_IN + rem);
    float vv[4] = {v.x, v.y, v.z, v.w};
    u16 hb[4], lb[4];
#pragma unroll
    for (int k = 0; k < 4; ++k) {
      hb[k] = f2bf(vv[k]);
      lb[k] = f2bf(vv[k] - bf2f(hb[k]));
    }
    hp.x = (u32)hb[0] | ((u32)hb[1] << 16);
    hp.y = (u32)hb[2] | ((u32)hb[3] << 16);
    lp.x = (u32)lb[0] | ((u32)lb[1] << 16);
    lp.y = (u32)lb[2] | ((u32)lb[3] << 16);
  }
  *(uint2*)(hi + o) = hp;
  *(uint2*)(lo + o) = lp;
}

__global__ void deg_kernel(const int* __restrict__ col, const float* __restrict__ w,
                           float* __restrict__ deg, int* __restrict__ counts) {
  int e = blockIdx.x * blockDim.x + threadIdx.x;
  if (e >= E_EDGES) return;
  int c = col[e];
  atomicAdd(&deg[c], w[e]);
  atomicAdd(&counts[c], 1);
}

__global__ void dinv_kernel(float* __restrict__ deg_dinv, float* __restrict__ selfw) {
  int n = blockIdx.x * blockDim.x + threadIdx.x;
  if (n >= N_NODES) return;
  float d = deg_dinv[n] + 1.0f;
  float di = 1.0f / sqrtf(d);
  deg_dinv[n] = di;
  selfw[n] = 1.0f / d;
}

__global__ __launch_bounds__(1024) void scan_kernel(const int* __restrict__ counts,
                                                    int* __restrict__ offsets, int n) {
  __shared__ int smem[1024];
  __shared__ int carry_s;
  if (threadIdx.x == 0) carry_s = 0;
  __syncthreads();
  for (int base = 0; base < n; base += 1024) {
    int i = base + threadIdx.x;
    int v = (i < n) ? counts[i] : 0;
    smem[threadIdx.x] = v;
    __syncthreads();
    for (int off = 1; off < 1024; off <<= 1) {
      int t = (threadIdx.x >= off) ? smem[threadIdx.x - off] : 0;
      __syncthreads();
      smem[threadIdx.x] += t;
      __syncthreads();
    }
    if (i < n) offsets[i] = carry_s + smem[threadIdx.x] - v;
    int total = smem[1023];
    __syncthreads();
    if (threadIdx.x == 0) carry_s += total;
    __syncthreads();
  }
  if (threadIdx.x == 0) offsets[n] = carry_s;
}

__global__ void scatter_kernel(const int* __restrict__ row, const int* __restrict__ col,
                               const float* __restrict__ w, const float* __restrict__ dinv,
                               const int* __restrict__ offsets, int* __restrict__ cursor,
                               int* __restrict__ csr_row, float* __restrict__ csr_norm) {
  int e = blockIdx.x * blockDim.x + threadIdx.x;
  if (e >= E_EDGES) return;
  int r = row[e], c = col[e];
  float nrm = dinv[r] * w[e] * dinv[c];
  int pos = offsets[c] + atomicAdd(&cursor[c], 1);
  csr_row[pos] = r;
  csr_norm[pos] = nrm;
}

// ---------------- GCN aggregation (fp16 hW) + relu (+ final lin) -----------
// fp32 accumulation (round-8 verified: absmax unchanged at 4.88e-4).
// Round-9: !FINAL writes fp16 G16 (conv input); FINAL writes bf16-split S.
__device__ __forceinline__ void fma8h(float* a, float w, const _Float16* p) {
  f16x4 x = *(const f16x4*)p;
  f16x4 y = *(const f16x4*)(p + 256);
  a[0] = fmaf(w, (float)x[0], a[0]);
  a[1] = fmaf(w, (float)x[1], a[1]);
  a[2] = fmaf(w, (float)x[2], a[2]);
  a[3] = fmaf(w, (float)x[3], a[3]);
  a[4] = fmaf(w, (float)y[0], a[4]);
  a[5] = fmaf(w, (float)y[1], a[5]);
  a[6] = fmaf(w, (float)y[2], a[6]);
  a[7] = fmaf(w, (float)y[3], a[7]);
}

template <bool FINAL>
__global__ __launch_bounds__(256) void agg_kernel(
    const _Float16* __restrict__ hW, const int* __restrict__ csr_row,
    const float* __restrict__ csr_norm, const int* __restrict__ offsets,
    const float* __restrict__ selfw, const float* __restrict__ bias,
    u16* __restrict__ Shi, u16* __restrict__ Slo,
    _Float16* __restrict__ G16out,
    const float* __restrict__ lw, const float* __restrict__ lb,
    float* __restrict__ out) {
  const int n = (blockIdx.x << 2) | (threadIdx.x >> 6);
  const int lane = threadIdx.x & 63;
  if (n >= N_NODES) return;
  const int c0 = lane << 2;
  const int beg = offsets[n], end = offsets[n + 1];
  float a0[8] = {}, a1[8] = {};
  int j = beg;
  for (; j + 4 <= end; j += 4) {
    int r0 = csr_row[j], r1 = csr_row[j + 1], r2 = csr_row[j + 2], r3 = csr_row[j + 3];
    float w0 = csr_norm[j], w1 = csr_norm[j + 1], w2 = csr_norm[j + 2], w3 = csr_norm[j + 3];
    fma8h(a0, w0, hW + (size_t)r0 * H_DIM + c0);
    fma8h(a1, w1, hW + (size_t)r1 * H_DIM + c0);
    fma8h(a0, w2, hW + (size_t)r2 * H_DIM + c0);
    fma8h(a1, w3, hW + (size_t)r3 * H_DIM + c0);
  }
  for (; j < end; ++j) fma8h(a0, csr_norm[j], hW + (size_t)csr_row[j] * H_DIM + c0);

  const float sw = selfw[n];
  const _Float16* ps = hW + (size_t)n * H_DIM + c0;
  f16x4 sa = *(const f16x4*)ps;
  f16x4 sb = *(const f16x4*)(ps + 256);
  float4 ba = *(const float4*)(bias + c0);
  float4 bb = *(const float4*)(bias + 256 + c0);
  float v[8];
  v[0] = fmaxf(fmaf(sw, (float)sa[0], a0[0] + a1[0]) + ba.x, 0.f);
  v[1] = fmaxf(fmaf(sw, (float)sa[1], a0[1] + a1[1]) + ba.y, 0.f);
  v[2] = fmaxf(fmaf(sw, (float)sa[2], a0[2] + a1[2]) + ba.z, 0.f);
  v[3] = fmaxf(fmaf(sw, (float)sa[3], a0[3] + a1[3]) + ba.w, 0.f);
  v[4] = fmaxf(fmaf(sw, (float)sb[0], a0[4] + a1[4]) + bb.x, 0.f);
  v[5] = fmaxf(fmaf(sw, (float)sb[1], a0[5] + a1[5]) + bb.y, 0.f);
  v[6] = fmaxf(fmaf(sw, (float)sb[2], a0[6] + a1[6]) + bb.z, 0.f);
  v[7] = fmaxf(fmaf(sw, (float)sb[3], a0[7] + a1[7]) + bb.w, 0.f);

  size_t o = (size_t)n * H_DIM + c0;
  if (FINAL) {
    u16 hb[8], lb2[8];
#pragma unroll
    for (int k = 0; k < 8; ++k) {
      hb[k] = f2bf(v[k]);
      lb2[k] = f2bf(v[k] - bf2f(hb[k]));
    }
    uint2 p;
    p.x = (u32)hb[0] | ((u32)hb[1] << 16);
    p.y = (u32)hb[2] | ((u32)hb[3] << 16);
    *(uint2*)(Shi + o) = p;
    p.x = (u32)hb[4] | ((u32)hb[5] << 16);
    p.y = (u32)hb[6] | ((u32)hb[7] << 16);
    *(uint2*)(Shi + o + 256) = p;
    p.x = (u32)lb2[0] | ((u32)lb2[1] << 16);
    p.y = (u32)lb2[2] | ((u32)lb2[3] << 16);
    *(uint2*)(Slo + o) = p;
    p.x = (u32)lb2[4] | ((u32)lb2[5] << 16);
    p.y = (u32)lb2[6] | ((u32)lb2[7] << 16);
    *(uint2*)(Slo + o + 256) = p;

    float4 la = *(const float4*)(lw + c0);
    float4 lbv = *(const float4*)(lw + 256 + c0);
    float s = v[0] * la.x + v[1] * la.y + v[2] * la.z + v[3] * la.w +
              v[4] * lbv.x + v[5] * lbv.y + v[6] * lbv.z + v[7] * lbv.w;
#pragma unroll
    for (int off2 = 32; off2 > 0; off2 >>= 1) s += __shfl_down(s, off2, 64);
    if (lane == 0) out[n] = s + lb[0];
  } else {
    f16x4 ga = {(_Float16)v[0], (_Float16)v[1], (_Float16)v[2], (_Float16)v[3]};
    f16x4 gb = {(_Float16)v[4], (_Float16)v[5], (_Float16)v[6], (_Float16)v[7]};
    *(f16x4*)(G16out + o) = ga;
    *(f16x4*)(G16out + o + 256) = gb;
  }
}

// ---------------- launch ----------------
extern "C" void kernel_launch(void* const* d_in, const int* in_sizes, int n_in,
                              void* d_out, int out_size, void* d_ws, size_t ws_size,
                              hipStream_t stream) {
  const float* xs = (const float*)d_in[0];
  const int* ei = (const int*)d_in[1];
  const float* ew = (const float*)d_in[2];
  const float* W_ih = (const float*)d_in[3];
  const float* W_hh = (const float*)d_in[4];
  const float* b_ih = (const float*)d_in[5];
  const float* b_hh = (const float*)d_in[6];
  const float* conv_W = (const float*)d_in[7];
  const float* conv_b = (const float*)d_in[8];
  const float* lin_W = (const float*)d_in[9];
  const float* lin_b = (const float*)d_in[10];
  float* out = (float*)d_out;

  const int* row = ei;
  const int* col = ei + E_EDGES;

  char* ws = (char*)d_ws;
  size_t off = 0;
  auto alloc = [&](size_t bytes) -> void* {
    void* p = ws + off;
    off += (bytes + 255) & ~(size_t)255;
    return p;
  };
  u16* S_hi = (u16*)alloc((size_t)MP * H_DIM * 2);  // h state splits
  u16* S_lo = (u16*)alloc((size_t)MP * H_DIM * 2);
  _Float16* G16 = (_Float16*)alloc((size_t)MP * H_DIM * 2);  // gate/agg0 out (fp16)
  _Float16* hW16 = (_Float16*)alloc((size_t)MP * H_DIM * 2);
  u16* xs_hi = (u16*)alloc((size_t)T_STEPS * MP * D_IN * 2);
  u16* xs_lo = (u16*)alloc((size_t)T_STEPS * MP * D_IN * 2);
  u16* WihG_hi = (u16*)alloc((size_t)H3 * D_IN * 2);
  u16* WihG_lo = (u16*)alloc((size_t)H3 * D_IN * 2);
  u16* WhhG_hi = (u16*)alloc((size_t)H3 * H_DIM * 2);
  u16* WhhG_lo = (u16*)alloc((size_t)H3 * H_DIM * 2);
  _Float16* Wc16 = (_Float16*)alloc((size_t)NUM_CONVS * H_DIM * H_DIM * 2);
  float* bihg = (float*)alloc(H3 * 4);
  float* bhhg = (float*)alloc(H3 * 4);
  float* dinv = (float*)alloc(N_NODES * 4);
  float* selfw = (float*)alloc(N_NODES * 4);
  float* csr_norm = (float*)alloc(E_EDGES * 4);
  int* csr_row = (int*)alloc(E_EDGES * 4);
  int* offsets = (int*)alloc((N_NODES + 1) * 4);
  int* counts = (int*)alloc(N_NODES * 4);
  int* cursor = (int*)alloc(N_NODES * 4);

  hipMemsetAsync(S_hi, 0, (size_t)MP * H_DIM * 2, stream);
  hipMemsetAsync(S_lo, 0, (size_t)MP * H_DIM * 2, stream);
  hipMemsetAsync(G16, 0, (size_t)MP * H_DIM * 2, stream);
  hipMemsetAsync(hW16, 0, (size_t)MP * H_DIM * 2, stream);
  hipMemsetAsync(dinv, 0, N_NODES * 4, stream);
  hipMemsetAsync(counts, 0, N_NODES * 4, stream);
  hipMemsetAsync(cursor, 0, N_NODES * 4, stream);

  // one-time preprocessing
  deg_kernel<<<(E_EDGES + 255) / 256, 256, 0, stream>>>(col, ew, dinv, counts);
  dinv_kernel<<<(N_NODES + 255) / 256, 256, 0, stream>>>(dinv, selfw);
  scan_kernel<<<1, 1024, 0, stream>>>(counts, offsets, N_NODES);
  scatter_kernel<<<(E_EDGES + 255) / 256, 256, 0, stream>>>(row, col, ew, dinv, offsets,
                                                            cursor, csr_row, csr_norm);
  split_grouped<<<(H3 * D_IN + 255) / 256, 256, 0, stream>>>(W_ih, WihG_hi, WihG_lo, D_IN);
  split_grouped<<<(H3 * H_DIM + 255) / 256, 256, 0, stream>>>(W_hh, WhhG_hi, WhhG_lo, H_DIM);
  bias_grouped<<<(H3 + 255) / 256, 256, 0, stream>>>(b_ih, b_hh, bihg, bhhg);
  split_convw<<<(NUM_CONVS * H_DIM * H_DIM + 255) / 256, 256, 0, stream>>>(conv_W, Wc16);
  split_xs<<<(T_STEPS * MP * D_IN / 4 + 255) / 256, 256, 0, stream>>>(xs, xs_hi, xs_lo);

  dim3 blk(256);
  dim3 g_gru(16, MP / 128);       // 2 jb per block x 79 row-blocks
  dim3 g_conv(H_DIM / 128, MP / 64);  // 4 x 158 = 632 blocks
  int g_agg = (N_NODES + 3) / 4;

  for (int t = 0; t < T_STEPS; ++t) {
    // fused: gi + gh GEMMs + GRU gate -> G16 (fp16)
    gru_fused<<<g_gru, blk, 0, stream>>>(
        xs_hi + (size_t)t * MP * D_IN, xs_lo + (size_t)t * MP * D_IN,
        S_hi, S_lo, WihG_hi, WihG_lo, WhhG_hi, WhhG_lo, bihg, bhhg, G16);
    // conv0: hW16 = G16 @ Wc0 ; agg0 -> G16
    gemm_conv<<<g_conv, blk, 0, stream>>>((const u16*)G16, (const u16*)Wc16, hW16,
                                          N_NODES, H_DIM, H_DIM);
    agg_kernel<false><<<g_agg, 256, 0, stream>>>(
        hW16, csr_row, csr_norm, offsets, selfw, conv_b, nullptr, nullptr, G16,
        nullptr, nullptr, nullptr);
    // conv1: hW16 = G16 @ Wc1 ; agg1(final) -> S state + fused linear
    gemm_conv<<<g_conv, blk, 0, stream>>>(
        (const u16*)G16, (const u16*)(Wc16 + (size_t)H_DIM * H_DIM), hW16,
        N_NODES, H_DIM, H_DIM);
    agg_kernel<true><<<g_agg, 256, 0, stream>>>(
        hW16, csr_row, csr_norm, offsets, selfw, conv_b + H_DIM, S_hi, S_lo, nullptr,
        lin_W, lin_b, out + (size_t)t * N_NODES);
  }
}

// Round 10
// 1652.017 us; speedup vs baseline: 1.5411x; 1.3296x over previous
//
#include <hip/hip_runtime.h>
#include <math.h>

#define T_STEPS 12
#define N_NODES 10000
#define MP 10112  // 79*128, padded M
#define D_IN 256
#define H_DIM 512
#define H3 1536
#define E_EDGES 160000
#define NUM_CONVS 2

typedef _Float16 f16x8 __attribute__((ext_vector_type(8)));
typedef float floatx4 __attribute__((ext_vector_type(4)));
typedef _Float16 f16x4 __attribute__((ext_vector_type(4)));
typedef unsigned short u16;
typedef unsigned int u32;

__device__ __forceinline__ float sigmoid_f(float x) {
  return __builtin_amdgcn_rcpf(1.0f + __expf(-x));
}
__device__ __forceinline__ float tanh_f(float x) {
  return 1.0f - 2.0f * __builtin_amdgcn_rcpf(1.0f + __expf(2.0f * x));
}

__device__ __forceinline__ void glds16(const void* g, void* l) {
  __builtin_amdgcn_global_load_lds(
      (const __attribute__((address_space(1))) unsigned int*)g,
      (__attribute__((address_space(3))) unsigned int*)l, 16, 0, 0);
}

#define MFMA16H(a, b, c) __builtin_amdgcn_mfma_f32_16x16x32_f16((a), (b), (c), 0, 0, 0)

// ============ fused GRU: fp16 single-product, 2-barrier + XCD swizzle =======
// Round-10: bf16x3 -> fp16 (12 MFMA/K-tile vs 36; staging loads halved; LDS
// 28.7->14.3 KB -> ~6 blocks/CU). Rationale: absmax was pinned at 2^-11 by
// the fp16 hW16 quantization through r7-r9 -- X (~N(0,1)) and h (|h|<=1)
// quantize to fp16 at the same error scale; GRU gating is contractive so
// state error doesn't compound. Gate math stays fp32.
// (round-7 lesson kept: single-buffer LDS + inter-block overlap beats dbuf.)
__global__ __launch_bounds__(256) void gru_fused(
    const _Float16* __restrict__ X16,   // (MP,256)
    const _Float16* __restrict__ S16,   // (MP,512) recurrent state (fp16)
    const _Float16* __restrict__ Wih,   // grouped (1536,256)
    const _Float16* __restrict__ Whh,   // grouped (1536,512)
    const float* __restrict__ bihg, const float* __restrict__ bhhg,
    _Float16* __restrict__ G16) {
  __shared__ _Float16 As[4096];  // 128 rows x 32 k, swizzled 16B slots
  __shared__ _Float16 Bs[3072];  // 96 rows x 32 k
  const int tid = threadIdx.x;
  const int lane = tid & 63;
  const int wave = tid >> 6;
  // T1: XCD-chunked swizzle; 1264 blocks = 8 * 158 (exactly divisible)
  const int bid = blockIdx.y * 16 + blockIdx.x;
  const int lid = (bid & 7) * 158 + (bid >> 3);
  const int bx = lid & 15, by = lid >> 4;
  const int rbase = by * 128;
  const int cbase = bx * 96;

  // slot decompositions (K-independent): As 512 slots, Bs 384 slots
  const int sa1 = tid, sa2 = tid + 256;
  const int ra1 = sa1 >> 2, ca1 = (sa1 & 3) ^ ((ra1 >> 1) & 3);
  const int ra2 = sa2 >> 2, ca2 = (sa2 & 3) ^ ((ra2 >> 1) & 3);
  const int la1 = (sa1 >> 6) << 9;
  const int la2 = (sa2 >> 6) << 9;
  const int sb1 = tid;
  const int rb1 = sb1 >> 2, cb1 = (sb1 & 3) ^ ((rb1 >> 1) & 3);
  const int lb1 = (sb1 >> 6) << 9;
  const int sb2 = 256 + tid;
  const int rb2 = sb2 >> 2, cb2 = (sb2 & 3) ^ ((rb2 >> 1) & 3);
  const int lb2 = (sb2 >> 6) << 9;

  const int wr = (wave >> 1) * 64;
  const int wc = (wave & 1) * 48;
  const int lrow = lane & 15;
  const int kq = lane >> 4;
  const int swz = kq ^ ((lrow >> 1) & 3);
  const int aoff = (wr + lrow) * 32 + swz * 8;
  const int boff = (wc + lrow) * 32 + swz * 8;

  floatx4 acc[4][4];  // [row-frag][gate: 0=r 1=z 2=ni 3=nh]
#pragma unroll
  for (int i = 0; i < 4; ++i)
#pragma unroll
    for (int g = 0; g < 4; ++g) acc[i][g] = (floatx4){0.f, 0.f, 0.f, 0.f};

  // ---------------- phase 1: x_t @ W_ih^T, K=256 ----------------
  {
    const _Float16* pa1 = X16 + (size_t)(rbase + ra1) * 256 + ca1 * 8;
    const _Float16* pa2 = X16 + (size_t)(rbase + ra2) * 256 + ca2 * 8;
    const _Float16* pb1 = Wih + (size_t)(cbase + rb1) * 256 + cb1 * 8;
    const _Float16* pb2 = Wih + (size_t)(cbase + rb2) * 256 + cb2 * 8;
    for (int kt = 0; kt < 256; kt += 32) {
      glds16(pa1 + kt, &As[la1]);
      glds16(pa2 + kt, &As[la2]);
      glds16(pb1 + kt, &Bs[lb1]);
      if (tid < 128) glds16(pb2 + kt, &Bs[lb2]);
      __syncthreads();
      f16x8 ah[4], bh[3];
#pragma unroll
      for (int i = 0; i < 4; ++i) ah[i] = *(const f16x8*)&As[aoff + i * 512];
#pragma unroll
      for (int g = 0; g < 3; ++g) bh[g] = *(const f16x8*)&Bs[boff + g * 512];
#pragma unroll
      for (int i = 0; i < 4; ++i) {
        acc[i][0] = MFMA16H(ah[i], bh[0], acc[i][0]);
        acc[i][1] = MFMA16H(ah[i], bh[1], acc[i][1]);
        acc[i][2] = MFMA16H(ah[i], bh[2], acc[i][2]);
      }
      __syncthreads();
    }
  }
  // ---------------- phase 2: h @ W_hh^T, K=512; n-group -> acc[.][3] -------
  {
    const _Float16* pa1 = S16 + (size_t)(rbase + ra1) * 512 + ca1 * 8;
    const _Float16* pa2 = S16 + (size_t)(rbase + ra2) * 512 + ca2 * 8;
    const _Float16* pb1 = Whh + (size_t)(cbase + rb1) * 512 + cb1 * 8;
    const _Float16* pb2 = Whh + (size_t)(cbase + rb2) * 512 + cb2 * 8;
    for (int kt = 0; kt < 512; kt += 32) {
      glds16(pa1 + kt, &As[la1]);
      glds16(pa2 + kt, &As[la2]);
      glds16(pb1 + kt, &Bs[lb1]);
      if (tid < 128) glds16(pb2 + kt, &Bs[lb2]);
      __syncthreads();
      f16x8 ah[4], bh[3];
#pragma unroll
      for (int i = 0; i < 4; ++i) ah[i] = *(const f16x8*)&As[aoff + i * 512];
#pragma unroll
      for (int g = 0; g < 3; ++g) bh[g] = *(const f16x8*)&Bs[boff + g * 512];
#pragma unroll
      for (int i = 0; i < 4; ++i) {
        acc[i][0] = MFMA16H(ah[i], bh[0], acc[i][0]);
        acc[i][1] = MFMA16H(ah[i], bh[1], acc[i][1]);
        acc[i][3] = MFMA16H(ah[i], bh[2], acc[i][3]);
      }
      __syncthreads();
    }
  }

  // ---------------- epilogue: GRU gate in registers ----------------
  const int c0g = cbase + wc + lrow;
  const int j = (((bx << 1) | (wave & 1)) << 4) | lrow;
  const float brz0 = bihg[c0g] + bhhg[c0g];
  const float brz1 = bihg[c0g + 16] + bhhg[c0g + 16];
  const float bin = bihg[c0g + 32];
  const float bhn = bhhg[c0g + 32];
#pragma unroll
  for (int i = 0; i < 4; ++i) {
    int r0 = rbase + wr + i * 16 + kq * 4;
#pragma unroll
    for (int rr = 0; rr < 4; ++rr) {
      int row = r0 + rr;
      if (row >= N_NODES) continue;
      float r = sigmoid_f(acc[i][0][rr] + brz0);
      float z = sigmoid_f(acc[i][1][rr] + brz1);
      float nn = tanh_f(acc[i][2][rr] + bin + r * (acc[i][3][rr] + bhn));
      size_t o = (size_t)row * H_DIM + j;
      float hp = (float)S16[o];
      float hv = (1.0f - z) * nn + z * hp;
      G16[o] = (_Float16)hv;
    }
  }
}

// ============ conv GEMM: 64x128 fp16 single-product, pipelined ==============
// (round-9 verified: fp16 conv chain, absmax unchanged at 4.88e-4)
__global__ __launch_bounds__(256) void gemm_conv(
    const u16* __restrict__ A16, const u16* __restrict__ B16,
    _Float16* __restrict__ C, int M, int Nn, int K) {
  __shared__ u16 As[2][2048];  // [buf] 64 rows x 32 k fp16
  __shared__ u16 Bs[2][4096];  // [buf] 128 rows x 32 k fp16
  const int tid = threadIdx.x;
  const int lane = tid & 63;
  const int wave = tid >> 6;
  // T1: XCD-chunked swizzle; 632 blocks = 8 * 79
  const int bid = blockIdx.y * 4 + blockIdx.x;
  const int lid = (bid & 7) * 79 + (bid >> 3);
  const int bx = lid & 3, by = lid >> 2;
  const int rbase = by * 64;
  const int cbase = bx * 128;

  const int sa = tid;
  const int ra = sa >> 2, ca = (sa & 3) ^ ((ra >> 1) & 3);
  const int la = (sa >> 6) << 9;
  const int sb1 = tid, sb2 = tid + 256;
  const int rb1 = sb1 >> 2, cb1 = (sb1 & 3) ^ ((rb1 >> 1) & 3);
  const int rb2 = sb2 >> 2, cb2 = (sb2 & 3) ^ ((rb2 >> 1) & 3);
  const int lb1 = (sb1 >> 6) << 9, lb2 = (sb2 >> 6) << 9;
  const size_t oA = (size_t)(rbase + ra) * K + ca * 8;
  const size_t oB1 = (size_t)(cbase + rb1) * K + cb1 * 8;
  const size_t oB2 = (size_t)(cbase + rb2) * K + cb2 * 8;

  const int wr = (wave >> 1) * 32;
  const int wc = (wave & 1) * 64;
  const int lrow = lane & 15;
  const int kq = lane >> 4;
  const int swz = kq ^ ((lrow >> 1) & 3);
  const int aoff = (wr + lrow) * 32 + swz * 8;
  const int boff = (wc + lrow) * 32 + swz * 8;

  auto stage = [&](int buf, int t) {  // 3 loads per thread, uniform
    const int kt = t * 32;
    glds16(A16 + oA + kt, &As[buf][la]);
    glds16(B16 + oB1 + kt, &Bs[buf][lb1]);
    glds16(B16 + oB2 + kt, &Bs[buf][lb2]);
  };

  floatx4 acc[2][4];
#pragma unroll
  for (int i = 0; i < 2; ++i)
#pragma unroll
    for (int jj = 0; jj < 4; ++jj) acc[i][jj] = (floatx4){0.f, 0.f, 0.f, 0.f};

  const int NT = K >> 5;  // 16
  stage(0, 0);
  stage(1, 1);
  int cur = 0;
  for (int t = 0; t < NT; ++t) {
    if (t < NT - 1) asm volatile("s_waitcnt vmcnt(3)" ::: "memory");
    else            asm volatile("s_waitcnt vmcnt(0)" ::: "memory");
    __builtin_amdgcn_s_barrier();
    __builtin_amdgcn_sched_barrier(0);
    {
      f16x8 ah[2], bh[4];
#pragma unroll
      for (int i = 0; i < 2; ++i) ah[i] = *(const f16x8*)&As[cur][aoff + i * 512];
#pragma unroll
      for (int jj = 0; jj < 4; ++jj) bh[jj] = *(const f16x8*)&Bs[cur][boff + jj * 512];
      __builtin_amdgcn_s_setprio(1);
#pragma unroll
      for (int i = 0; i < 2; ++i)
#pragma unroll
        for (int jj = 0; jj < 4; ++jj) acc[i][jj] = MFMA16H(ah[i], bh[jj], acc[i][jj]);
      __builtin_amdgcn_s_setprio(0);
      __builtin_amdgcn_s_barrier();  // reads retired before re-staging buf
    }
    __builtin_amdgcn_sched_barrier(0);
    if (t + 2 < NT) stage(cur, t + 2);
    cur ^= 1;
  }

#pragma unroll
  for (int jj = 0; jj < 4; ++jj) {
    int col = cbase + wc + jj * 16 + lrow;
#pragma unroll
    for (int i = 0; i < 2; ++i) {
      int r0 = rbase + wr + i * 16 + kq * 4;
#pragma unroll
      for (int rr = 0; rr < 4; ++rr) {
        int row = r0 + rr;
        if (row < M) C[(size_t)row * Nn + col] = (_Float16)acc[i][jj][rr];
      }
    }
  }
}

// ---------------- split / preprocessing kernels ----------------
// W[3H][K] -> grouped fp16: new_row = (j>>4)*48 + g*16 + (j&15), g=row/512
__global__ void split_grouped16(const float* __restrict__ W, _Float16* __restrict__ w16,
                                int K) {
  int i = blockIdx.x * 256 + threadIdx.x;
  if (i >= H3 * K) return;
  int r3h = i / K, k = i - r3h * K;
  int g = r3h >> 9, j = r3h & 511;
  int nr = ((j >> 4) * 48) + (g << 4) + (j & 15);
  w16[(size_t)nr * K + k] = (_Float16)W[i];
}

__global__ void bias_grouped(const float* __restrict__ bih, const float* __restrict__ bhh,
                             float* __restrict__ bihg, float* __restrict__ bhhg) {
  int n = blockIdx.x * 256 + threadIdx.x;
  if (n >= H3) return;
  int g = n >> 9, j = n & 511;
  int nr = ((j >> 4) * 48) + (g << 4) + (j & 15);
  bihg[nr] = bih[n];
  bhhg[nr] = bhh[n];
}

// conv_W[l][k][j] -> transposed fp16 [l][j][k]
__global__ void split_convw(const float* __restrict__ W, _Float16* __restrict__ w16) {
  int o = blockIdx.x * 256 + threadIdx.x;
  if (o >= NUM_CONVS * H_DIM * H_DIM) return;
  int k = o & 511, j = (o >> 9) & 511, l = o >> 18;
  float v = W[(size_t)l * H_DIM * H_DIM + (size_t)k * H_DIM + j];
  w16[o] = (_Float16)v;
}

// xs (T,N,D) -> padded (T,MP,D) fp16; pad rows zeroed
__global__ void split_xs16(const float* __restrict__ xs, _Float16* __restrict__ x16) {
  const int QP = MP * D_IN / 4;
  int q = blockIdx.x * 256 + threadIdx.x;
  if (q >= T_STEPS * QP) return;
  int t = q / QP;
  int rem = (q - t * QP) * 4;
  size_t o = (size_t)t * MP * D_IN + rem;
  f16x4 v16 = {(_Float16)0.f, (_Float16)0.f, (_Float16)0.f, (_Float16)0.f};
  if (rem < N_NODES * D_IN) {
    float4 v = *(const float4*)(xs + (size_t)t * N_NODES * D_IN + rem);
    v16[0] = (_Float16)v.x;
    v16[1] = (_Float16)v.y;
    v16[2] = (_Float16)v.z;
    v16[3] = (_Float16)v.w;
  }
  *(f16x4*)(x16 + o) = v16;
}

__global__ void deg_kernel(const int* __restrict__ col, const float* __restrict__ w,
                           float* __restrict__ deg, int* __restrict__ counts) {
  int e = blockIdx.x * blockDim.x + threadIdx.x;
  if (e >= E_EDGES) return;
  int c = col[e];
  atomicAdd(&deg[c], w[e]);
  atomicAdd(&counts[c], 1);
}

__global__ void dinv_kernel(float* __restrict__ deg_dinv, float* __restrict__ selfw) {
  int n = blockIdx.x * blockDim.x + threadIdx.x;
  if (n >= N_NODES) return;
  float d = deg_dinv[n] + 1.0f;
  float di = 1.0f / sqrtf(d);
  deg_dinv[n] = di;
  selfw[n] = 1.0f / d;
}

__global__ __launch_bounds__(1024) void scan_kernel(const int* __restrict__ counts,
                                                    int* __restrict__ offsets, int n) {
  __shared__ int smem[1024];
  __shared__ int carry_s;
  if (threadIdx.x == 0) carry_s = 0;
  __syncthreads();
  for (int base = 0; base < n; base += 1024) {
    int i = base + threadIdx.x;
    int v = (i < n) ? counts[i] : 0;
    smem[threadIdx.x] = v;
    __syncthreads();
    for (int off = 1; off < 1024; off <<= 1) {
      int t = (threadIdx.x >= off) ? smem[threadIdx.x - off] : 0;
      __syncthreads();
      smem[threadIdx.x] += t;
      __syncthreads();
    }
    if (i < n) offsets[i] = carry_s + smem[threadIdx.x] - v;
    int total = smem[1023];
    __syncthreads();
    if (threadIdx.x == 0) carry_s += total;
    __syncthreads();
  }
  if (threadIdx.x == 0) offsets[n] = carry_s;
}

__global__ void scatter_kernel(const int* __restrict__ row, const int* __restrict__ col,
                               const float* __restrict__ w, const float* __restrict__ dinv,
                               const int* __restrict__ offsets, int* __restrict__ cursor,
                               int* __restrict__ csr_row, float* __restrict__ csr_norm) {
  int e = blockIdx.x * blockDim.x + threadIdx.x;
  if (e >= E_EDGES) return;
  int r = row[e], c = col[e];
  float nrm = dinv[r] * w[e] * dinv[c];
  int pos = offsets[c] + atomicAdd(&cursor[c], 1);
  csr_row[pos] = r;
  csr_norm[pos] = nrm;
}

// ---------------- GCN aggregation (fp16 hW) + relu (+ final lin) -----------
// fp32 accumulation (round-8 verified). dst is fp16: G16 for layer 0,
// S16 (recurrent state) for the final layer.
__device__ __forceinline__ void fma8h(float* a, float w, const _Float16* p) {
  f16x4 x = *(const f16x4*)p;
  f16x4 y = *(const f16x4*)(p + 256);
  a[0] = fmaf(w, (float)x[0], a[0]);
  a[1] = fmaf(w, (float)x[1], a[1]);
  a[2] = fmaf(w, (float)x[2], a[2]);
  a[3] = fmaf(w, (float)x[3], a[3]);
  a[4] = fmaf(w, (float)y[0], a[4]);
  a[5] = fmaf(w, (float)y[1], a[5]);
  a[6] = fmaf(w, (float)y[2], a[6]);
  a[7] = fmaf(w, (float)y[3], a[7]);
}

template <bool FINAL>
__global__ __launch_bounds__(256) void agg_kernel(
    const _Float16* __restrict__ hW, const int* __restrict__ csr_row,
    const float* __restrict__ csr_norm, const int* __restrict__ offsets,
    const float* __restrict__ selfw, const float* __restrict__ bias,
    _Float16* __restrict__ dst,
    const float* __restrict__ lw, const float* __restrict__ lb,
    float* __restrict__ out) {
  const int n = (blockIdx.x << 2) | (threadIdx.x >> 6);
  const int lane = threadIdx.x & 63;
  if (n >= N_NODES) return;
  const int c0 = lane << 2;
  const int beg = offsets[n], end = offsets[n + 1];
  float a0[8] = {}, a1[8] = {};
  int j = beg;
  for (; j + 4 <= end; j += 4) {
    int r0 = csr_row[j], r1 = csr_row[j + 1], r2 = csr_row[j + 2], r3 = csr_row[j + 3];
    float w0 = csr_norm[j], w1 = csr_norm[j + 1], w2 = csr_norm[j + 2], w3 = csr_norm[j + 3];
    fma8h(a0, w0, hW + (size_t)r0 * H_DIM + c0);
    fma8h(a1, w1, hW + (size_t)r1 * H_DIM + c0);
    fma8h(a0, w2, hW + (size_t)r2 * H_DIM + c0);
    fma8h(a1, w3, hW + (size_t)r3 * H_DIM + c0);
  }
  for (; j < end; ++j) fma8h(a0, csr_norm[j], hW + (size_t)csr_row[j] * H_DIM + c0);

  const float sw = selfw[n];
  const _Float16* ps = hW + (size_t)n * H_DIM + c0;
  f16x4 sa = *(const f16x4*)ps;
  f16x4 sb = *(const f16x4*)(ps + 256);
  float4 ba = *(const float4*)(bias + c0);
  float4 bb = *(const float4*)(bias + 256 + c0);
  float v[8];
  v[0] = fmaxf(fmaf(sw, (float)sa[0], a0[0] + a1[0]) + ba.x, 0.f);
  v[1] = fmaxf(fmaf(sw, (float)sa[1], a0[1] + a1[1]) + ba.y, 0.f);
  v[2] = fmaxf(fmaf(sw, (float)sa[2], a0[2] + a1[2]) + ba.z, 0.f);
  v[3] = fmaxf(fmaf(sw, (float)sa[3], a0[3] + a1[3]) + ba.w, 0.f);
  v[4] = fmaxf(fmaf(sw, (float)sb[0], a0[4] + a1[4]) + bb.x, 0.f);
  v[5] = fmaxf(fmaf(sw, (float)sb[1], a0[5] + a1[5]) + bb.y, 0.f);
  v[6] = fmaxf(fmaf(sw, (float)sb[2], a0[6] + a1[6]) + bb.z, 0.f);
  v[7] = fmaxf(fmaf(sw, (float)sb[3], a0[7] + a1[7]) + bb.w, 0.f);

  size_t o = (size_t)n * H_DIM + c0;
  f16x4 ga = {(_Float16)v[0], (_Float16)v[1], (_Float16)v[2], (_Float16)v[3]};
  f16x4 gb = {(_Float16)v[4], (_Float16)v[5], (_Float16)v[6], (_Float16)v[7]};
  *(f16x4*)(dst + o) = ga;
  *(f16x4*)(dst + o + 256) = gb;

  if (FINAL) {
    float4 la = *(const float4*)(lw + c0);
    float4 lbv = *(const float4*)(lw + 256 + c0);
    float s = v[0] * la.x + v[1] * la.y + v[2] * la.z + v[3] * la.w +
              v[4] * lbv.x + v[5] * lbv.y + v[6] * lbv.z + v[7] * lbv.w;
#pragma unroll
    for (int off2 = 32; off2 > 0; off2 >>= 1) s += __shfl_down(s, off2, 64);
    if (lane == 0) out[n] = s + lb[0];
  }
}

// ---------------- launch ----------------
extern "C" void kernel_launch(void* const* d_in, const int* in_sizes, int n_in,
                              void* d_out, int out_size, void* d_ws, size_t ws_size,
                              hipStream_t stream) {
  const float* xs = (const float*)d_in[0];
  const int* ei = (const int*)d_in[1];
  const float* ew = (const float*)d_in[2];
  const float* W_ih = (const float*)d_in[3];
  const float* W_hh = (const float*)d_in[4];
  const float* b_ih = (const float*)d_in[5];
  const float* b_hh = (const float*)d_in[6];
  const float* conv_W = (const float*)d_in[7];
  const float* conv_b = (const float*)d_in[8];
  const float* lin_W = (const float*)d_in[9];
  const float* lin_b = (const float*)d_in[10];
  float* out = (float*)d_out;

  const int* row = ei;
  const int* col = ei + E_EDGES;

  char* ws = (char*)d_ws;
  size_t off = 0;
  auto alloc = [&](size_t bytes) -> void* {
    void* p = ws + off;
    off += (bytes + 255) & ~(size_t)255;
    return p;
  };
  _Float16* S16 = (_Float16*)alloc((size_t)MP * H_DIM * 2);   // recurrent state
  _Float16* G16 = (_Float16*)alloc((size_t)MP * H_DIM * 2);   // gate/agg0 out
  _Float16* hW16 = (_Float16*)alloc((size_t)MP * H_DIM * 2);
  _Float16* xs16 = (_Float16*)alloc((size_t)T_STEPS * MP * D_IN * 2);
  _Float16* Wih16 = (_Float16*)alloc((size_t)H3 * D_IN * 2);
  _Float16* Whh16 = (_Float16*)alloc((size_t)H3 * H_DIM * 2);
  _Float16* Wc16 = (_Float16*)alloc((size_t)NUM_CONVS * H_DIM * H_DIM * 2);
  float* bihg = (float*)alloc(H3 * 4);
  float* bhhg = (float*)alloc(H3 * 4);
  float* dinv = (float*)alloc(N_NODES * 4);
  float* selfw = (float*)alloc(N_NODES * 4);
  float* csr_norm = (float*)alloc(E_EDGES * 4);
  int* csr_row = (int*)alloc(E_EDGES * 4);
  int* offsets = (int*)alloc((N_NODES + 1) * 4);
  int* counts = (int*)alloc(N_NODES * 4);
  int* cursor = (int*)alloc(N_NODES * 4);

  hipMemsetAsync(S16, 0, (size_t)MP * H_DIM * 2, stream);
  hipMemsetAsync(G16, 0, (size_t)MP * H_DIM * 2, stream);
  hipMemsetAsync(hW16, 0, (size_t)MP * H_DIM * 2, stream);
  hipMemsetAsync(dinv, 0, N_NODES * 4, stream);
  hipMemsetAsync(counts, 0, N_NODES * 4, stream);
  hipMemsetAsync(cursor, 0, N_NODES * 4, stream);

  // one-time preprocessing
  deg_kernel<<<(E_EDGES + 255) / 256, 256, 0, stream>>>(col, ew, dinv, counts);
  dinv_kernel<<<(N_NODES + 255) / 256, 256, 0, stream>>>(dinv, selfw);
  scan_kernel<<<1, 1024, 0, stream>>>(counts, offsets, N_NODES);
  scatter_kernel<<<(E_EDGES + 255) / 256, 256, 0, stream>>>(row, col, ew, dinv, offsets,
                                                            cursor, csr_row, csr_norm);
  split_grouped16<<<(H3 * D_IN + 255) / 256, 256, 0, stream>>>(W_ih, Wih16, D_IN);
  split_grouped16<<<(H3 * H_DIM + 255) / 256, 256, 0, stream>>>(W_hh, Whh16, H_DIM);
  bias_grouped<<<(H3 + 255) / 256, 256, 0, stream>>>(b_ih, b_hh, bihg, bhhg);
  split_convw<<<(NUM_CONVS * H_DIM * H_DIM + 255) / 256, 256, 0, stream>>>(conv_W, Wc16);
  split_xs16<<<(T_STEPS * MP * D_IN / 4 + 255) / 256, 256, 0, stream>>>(xs, xs16);

  dim3 blk(256);
  dim3 g_gru(16, MP / 128);       // 2 jb per block x 79 row-blocks
  dim3 g_conv(H_DIM / 128, MP / 64);  // 4 x 158 = 632 blocks
  int g_agg = (N_NODES + 3) / 4;

  for (int t = 0; t < T_STEPS; ++t) {
    // fused: gi + gh GEMMs + GRU gate -> G16 (fp16)
    gru_fused<<<g_gru, blk, 0, stream>>>(
        xs16 + (size_t)t * MP * D_IN, S16, Wih16, Whh16, bihg, bhhg, G16);
    // conv0: hW16 = G16 @ Wc0 ; agg0 -> G16
    gemm_conv<<<g_conv, blk, 0, stream>>>((const u16*)G16, (const u16*)Wc16, hW16,
                                          N_NODES, H_DIM, H_DIM);
    agg_kernel<false><<<g_agg, 256, 0, stream>>>(
        hW16, csr_row, csr_norm, offsets, selfw, conv_b, G16,
        nullptr, nullptr, nullptr);
    // conv1: hW16 = G16 @ Wc1 ; agg1(final) -> S16 state + fused linear
    gemm_conv<<<g_conv, blk, 0, stream>>>(
        (const u16*)G16, (const u16*)(Wc16 + (size_t)H_DIM * H_DIM), hW16,
        N_NODES, H_DIM, H_DIM);
    agg_kernel<true><<<g_agg, 256, 0, stream>>>(
        hW16, csr_row, csr_norm, offsets, selfw, conv_b + H_DIM, S16,
        lin_W, lin_b, out + (size_t)t * N_NODES);
  }
}

// Round 11
// 1621.430 us; speedup vs baseline: 1.5702x; 1.0189x over previous
//
#include <hip/hip_runtime.h>
#include <math.h>

#define T_STEPS 12
#define N_NODES 10000
#define MP 10112  // 79*128, padded M
#define D_IN 256
#define H_DIM 512
#define H3 1536
#define E_EDGES 160000
#define NUM_CONVS 2

typedef _Float16 f16x8 __attribute__((ext_vector_type(8)));
typedef float floatx4 __attribute__((ext_vector_type(4)));
typedef _Float16 f16x4 __attribute__((ext_vector_type(4)));
typedef unsigned short u16;
typedef unsigned int u32;

__device__ __forceinline__ float sigmoid_f(float x) {
  return __builtin_amdgcn_rcpf(1.0f + __expf(-x));
}
__device__ __forceinline__ float tanh_f(float x) {
  return 1.0f - 2.0f * __builtin_amdgcn_rcpf(1.0f + __expf(2.0f * x));
}

__device__ __forceinline__ void glds16(const void* g, void* l) {
  __builtin_amdgcn_global_load_lds(
      (const __attribute__((address_space(1))) unsigned int*)g,
      (__attribute__((address_space(3))) unsigned int*)l, 16, 0, 0);
}

#define MFMA16H(a, b, c) __builtin_amdgcn_mfma_f32_16x16x32_f16((a), (b), (c), 0, 0, 0)

// One gru K-tile: 7 LDS reads + 12 MFMA (setprio-wrapped) + closing barrier.
// G2 = accumulator slot for the 3rd column group (2 in phase-1, 3 in phase-2),
// compile-time so acc stays statically indexed (rule #20).
template <int G2>
__device__ __forceinline__ void gru_kstep(const _Float16 (&As)[2][4096],
                                          const _Float16 (&Bs)[2][3072], int cur,
                                          int aoff, int boff,
                                          floatx4 (&acc)[4][4]) {
  f16x8 ah[4], bh[3];
#pragma unroll
  for (int i = 0; i < 4; ++i) ah[i] = *(const f16x8*)&As[cur][aoff + i * 512];
#pragma unroll
  for (int g = 0; g < 3; ++g) bh[g] = *(const f16x8*)&Bs[cur][boff + g * 512];
  __builtin_amdgcn_s_setprio(1);
#pragma unroll
  for (int i = 0; i < 4; ++i) {
    acc[i][0] = MFMA16H(ah[i], bh[0], acc[i][0]);
    acc[i][1] = MFMA16H(ah[i], bh[1], acc[i][1]);
    acc[i][G2] = MFMA16H(ah[i], bh[2], acc[i][G2]);
  }
  __builtin_amdgcn_s_setprio(0);
  __builtin_amdgcn_s_barrier();  // reads retired -> safe to restage this buf
}

// ============ fused GRU: fp16, 2-deep counted-vmcnt pipeline ================
// Round-11: round-1/4's pipelined schedule (correctness HW-validated in r4;
// its r4 regression was the bf16 57KB dbuf cutting residency 5->2 blocks).
// fp16 dbuf = 28KB -> 5 blocks/CU permitted -> drain removal should now pay.
// Counted vmcnt never 0 mid-loop; single 24-tile pipeline spans both phases.
__global__ __launch_bounds__(256) void gru_fused(
    const _Float16* __restrict__ X16,   // (MP,256)
    const _Float16* __restrict__ S16,   // (MP,512) recurrent state (fp16)
    const _Float16* __restrict__ Wih,   // grouped (1536,256)
    const _Float16* __restrict__ Whh,   // grouped (1536,512)
    const float* __restrict__ bihg, const float* __restrict__ bhhg,
    _Float16* __restrict__ G16) {
  __shared__ _Float16 As[2][4096];  // [buf] 128 rows x 32 k, swizzled slots
  __shared__ _Float16 Bs[2][3072];  // [buf] 96 rows x 32 k
  const int tid = threadIdx.x;
  const int lane = tid & 63;
  const int wave = tid >> 6;
  // T1: XCD-chunked swizzle; 1264 blocks = 8 * 158 (exactly divisible)
  const int bid = blockIdx.y * 16 + blockIdx.x;
  const int lid = (bid & 7) * 158 + (bid >> 3);
  const int bx = lid & 15, by = lid >> 4;
  const int rbase = by * 128;
  const int cbase = bx * 96;

  // slot decompositions (K-independent): As 512 slots, Bs 384 slots
  const int sa1 = tid, sa2 = tid + 256;
  const int ra1 = sa1 >> 2, ca1 = (sa1 & 3) ^ ((ra1 >> 1) & 3);
  const int ra2 = sa2 >> 2, ca2 = (sa2 & 3) ^ ((ra2 >> 1) & 3);
  const int la1 = (sa1 >> 6) << 9;
  const int la2 = (sa2 >> 6) << 9;
  const int sb1 = tid;
  const int rb1 = sb1 >> 2, cb1 = (sb1 & 3) ^ ((rb1 >> 1) & 3);
  const int lb1 = (sb1 >> 6) << 9;
  const int sb2 = 256 + tid;
  const int rb2 = sb2 >> 2, cb2 = (sb2 & 3) ^ ((rb2 >> 1) & 3);
  const int lb2 = (sb2 >> 6) << 9;

  const int wr = (wave >> 1) * 64;
  const int wc = (wave & 1) * 48;
  const int lrow = lane & 15;
  const int kq = lane >> 4;
  const int swz = kq ^ ((lrow >> 1) & 3);
  const int aoff = (wr + lrow) * 32 + swz * 8;
  const int boff = (wc + lrow) * 32 + swz * 8;

  // global element offsets for both phases
  const size_t xA1 = (size_t)(rbase + ra1) * 256 + ca1 * 8;
  const size_t xA2 = (size_t)(rbase + ra2) * 256 + ca2 * 8;
  const size_t hA1 = (size_t)(rbase + ra1) * 512 + ca1 * 8;
  const size_t hA2 = (size_t)(rbase + ra2) * 512 + ca2 * 8;
  const size_t xB1 = (size_t)(cbase + rb1) * 256 + cb1 * 8;
  const size_t xB2 = (size_t)(cbase + rb2) * 256 + cb2 * 8;
  const size_t hB1 = (size_t)(cbase + rb1) * 512 + cb1 * 8;
  const size_t hB2 = (size_t)(cbase + rb2) * 512 + cb2 * 8;

  // stage tile t (t<8: phase-1 X/Wih, t>=8: phase-2 S/Whh) into buffer buf.
  // Per-wave load count: waves 0-1 -> 4, waves 2-3 -> 3 (wave-uniform).
  auto stage = [&](int buf, int t) {
    if (t < 8) {
      const int kt = t * 32;
      glds16(X16 + xA1 + kt, &As[buf][la1]);
      glds16(X16 + xA2 + kt, &As[buf][la2]);
      glds16(Wih + xB1 + kt, &Bs[buf][lb1]);
      if (tid < 128) glds16(Wih + xB2 + kt, &Bs[buf][lb2]);
    } else {
      const int kt = (t - 8) * 32;
      glds16(S16 + hA1 + kt, &As[buf][la1]);
      glds16(S16 + hA2 + kt, &As[buf][la2]);
      glds16(Whh + hB1 + kt, &Bs[buf][lb1]);
      if (tid < 128) glds16(Whh + hB2 + kt, &Bs[buf][lb2]);
    }
  };

  floatx4 acc[4][4];  // [row-frag][gate: 0=r 1=z 2=ni 3=nh]
#pragma unroll
  for (int i = 0; i < 4; ++i)
#pragma unroll
    for (int g = 0; g < 4; ++g) acc[i][g] = (floatx4){0.f, 0.f, 0.f, 0.f};

  // ---- pipelined 24-tile K-loop (8 phase-1 + 16 phase-2, no mid drain) ----
  stage(0, 0);
  stage(1, 1);
  int cur = 0;
  for (int t = 0; t < 8; ++t) {
    if (wave < 2) asm volatile("s_waitcnt vmcnt(4)" ::: "memory");
    else          asm volatile("s_waitcnt vmcnt(3)" ::: "memory");
    __builtin_amdgcn_s_barrier();
    __builtin_amdgcn_sched_barrier(0);
    gru_kstep<2>(As, Bs, cur, aoff, boff, acc);
    __builtin_amdgcn_sched_barrier(0);
    stage(cur, t + 2);
    cur ^= 1;
  }
  for (int t = 8; t < 24; ++t) {
    if (t < 23) {
      if (wave < 2) asm volatile("s_waitcnt vmcnt(4)" ::: "memory");
      else          asm volatile("s_waitcnt vmcnt(3)" ::: "memory");
    } else {
      asm volatile("s_waitcnt vmcnt(0)" ::: "memory");
    }
    __builtin_amdgcn_s_barrier();
    __builtin_amdgcn_sched_barrier(0);
    gru_kstep<3>(As, Bs, cur, aoff, boff, acc);
    __builtin_amdgcn_sched_barrier(0);
    if (t + 2 < 24) stage(cur, t + 2);
    cur ^= 1;
  }

  // ---------------- epilogue: GRU gate in registers ----------------
  const int c0g = cbase + wc + lrow;
  const int j = (((bx << 1) | (wave & 1)) << 4) | lrow;
  const float brz0 = bihg[c0g] + bhhg[c0g];
  const float brz1 = bihg[c0g + 16] + bhhg[c0g + 16];
  const float bin = bihg[c0g + 32];
  const float bhn = bhhg[c0g + 32];
#pragma unroll
  for (int i = 0; i < 4; ++i) {
    int r0 = rbase + wr + i * 16 + kq * 4;
#pragma unroll
    for (int rr = 0; rr < 4; ++rr) {
      int row = r0 + rr;
      if (row >= N_NODES) continue;
      float r = sigmoid_f(acc[i][0][rr] + brz0);
      float z = sigmoid_f(acc[i][1][rr] + brz1);
      float nn = tanh_f(acc[i][2][rr] + bin + r * (acc[i][3][rr] + bhn));
      size_t o = (size_t)row * H_DIM + j;
      float hp = (float)S16[o];
      float hv = (1.0f - z) * nn + z * hp;
      G16[o] = (_Float16)hv;
    }
  }
}

// ============ conv GEMM: 64x128 fp16 single-product, pipelined ==============
// (round-9/10 verified: fp16 conv chain, absmax unchanged at 4.88e-4)
__global__ __launch_bounds__(256) void gemm_conv(
    const u16* __restrict__ A16, const u16* __restrict__ B16,
    _Float16* __restrict__ C, int M, int Nn, int K) {
  __shared__ u16 As[2][2048];  // [buf] 64 rows x 32 k fp16
  __shared__ u16 Bs[2][4096];  // [buf] 128 rows x 32 k fp16
  const int tid = threadIdx.x;
  const int lane = tid & 63;
  const int wave = tid >> 6;
  // T1: XCD-chunked swizzle; 632 blocks = 8 * 79
  const int bid = blockIdx.y * 4 + blockIdx.x;
  const int lid = (bid & 7) * 79 + (bid >> 3);
  const int bx = lid & 3, by = lid >> 2;
  const int rbase = by * 64;
  const int cbase = bx * 128;

  const int sa = tid;
  const int ra = sa >> 2, ca = (sa & 3) ^ ((ra >> 1) & 3);
  const int la = (sa >> 6) << 9;
  const int sb1 = tid, sb2 = tid + 256;
  const int rb1 = sb1 >> 2, cb1 = (sb1 & 3) ^ ((rb1 >> 1) & 3);
  const int rb2 = sb2 >> 2, cb2 = (sb2 & 3) ^ ((rb2 >> 1) & 3);
  const int lb1 = (sb1 >> 6) << 9, lb2 = (sb2 >> 6) << 9;
  const size_t oA = (size_t)(rbase + ra) * K + ca * 8;
  const size_t oB1 = (size_t)(cbase + rb1) * K + cb1 * 8;
  const size_t oB2 = (size_t)(cbase + rb2) * K + cb2 * 8;

  const int wr = (wave >> 1) * 32;
  const int wc = (wave & 1) * 64;
  const int lrow = lane & 15;
  const int kq = lane >> 4;
  const int swz = kq ^ ((lrow >> 1) & 3);
  const int aoff = (wr + lrow) * 32 + swz * 8;
  const int boff = (wc + lrow) * 32 + swz * 8;

  auto stage = [&](int buf, int t) {  // 3 loads per thread, uniform
    const int kt = t * 32;
    glds16(A16 + oA + kt, &As[buf][la]);
    glds16(B16 + oB1 + kt, &Bs[buf][lb1]);
    glds16(B16 + oB2 + kt, &Bs[buf][lb2]);
  };

  floatx4 acc[2][4];
#pragma unroll
  for (int i = 0; i < 2; ++i)
#pragma unroll
    for (int jj = 0; jj < 4; ++jj) acc[i][jj] = (floatx4){0.f, 0.f, 0.f, 0.f};

  const int NT = K >> 5;  // 16
  stage(0, 0);
  stage(1, 1);
  int cur = 0;
  for (int t = 0; t < NT; ++t) {
    if (t < NT - 1) asm volatile("s_waitcnt vmcnt(3)" ::: "memory");
    else            asm volatile("s_waitcnt vmcnt(0)" ::: "memory");
    __builtin_amdgcn_s_barrier();
    __builtin_amdgcn_sched_barrier(0);
    {
      f16x8 ah[2], bh[4];
#pragma unroll
      for (int i = 0; i < 2; ++i) ah[i] = *(const f16x8*)&As[cur][aoff + i * 512];
#pragma unroll
      for (int jj = 0; jj < 4; ++jj) bh[jj] = *(const f16x8*)&Bs[cur][boff + jj * 512];
      __builtin_amdgcn_s_setprio(1);
#pragma unroll
      for (int i = 0; i < 2; ++i)
#pragma unroll
        for (int jj = 0; jj < 4; ++jj) acc[i][jj] = MFMA16H(ah[i], bh[jj], acc[i][jj]);
      __builtin_amdgcn_s_setprio(0);
      __builtin_amdgcn_s_barrier();  // reads retired before re-staging buf
    }
    __builtin_amdgcn_sched_barrier(0);
    if (t + 2 < NT) stage(cur, t + 2);
    cur ^= 1;
  }

#pragma unroll
  for (int jj = 0; jj < 4; ++jj) {
    int col = cbase + wc + jj * 16 + lrow;
#pragma unroll
    for (int i = 0; i < 2; ++i) {
      int r0 = rbase + wr + i * 16 + kq * 4;
#pragma unroll
      for (int rr = 0; rr < 4; ++rr) {
        int row = r0 + rr;
        if (row < M) C[(size_t)row * Nn + col] = (_Float16)acc[i][jj][rr];
      }
    }
  }
}

// ---------------- split / preprocessing kernels ----------------
__global__ void split_grouped16(const float* __restrict__ W, _Float16* __restrict__ w16,
                                int K) {
  int i = blockIdx.x * 256 + threadIdx.x;
  if (i >= H3 * K) return;
  int r3h = i / K, k = i - r3h * K;
  int g = r3h >> 9, j = r3h & 511;
  int nr = ((j >> 4) * 48) + (g << 4) + (j & 15);
  w16[(size_t)nr * K + k] = (_Float16)W[i];
}

__global__ void bias_grouped(const float* __restrict__ bih, const float* __restrict__ bhh,
                             float* __restrict__ bihg, float* __restrict__ bhhg) {
  int n = blockIdx.x * 256 + threadIdx.x;
  if (n >= H3) return;
  int g = n >> 9, j = n & 511;
  int nr = ((j >> 4) * 48) + (g << 4) + (j & 15);
  bihg[nr] = bih[n];
  bhhg[nr] = bhh[n];
}

__global__ void split_convw(const float* __restrict__ W, _Float16* __restrict__ w16) {
  int o = blockIdx.x * 256 + threadIdx.x;
  if (o >= NUM_CONVS * H_DIM * H_DIM) return;
  int k = o & 511, j = (o >> 9) & 511, l = o >> 18;
  float v = W[(size_t)l * H_DIM * H_DIM + (size_t)k * H_DIM + j];
  w16[o] = (_Float16)v;
}

__global__ void split_xs16(const float* __restrict__ xs, _Float16* __restrict__ x16) {
  const int QP = MP * D_IN / 4;
  int q = blockIdx.x * 256 + threadIdx.x;
  if (q >= T_STEPS * QP) return;
  int t = q / QP;
  int rem = (q - t * QP) * 4;
  size_t o = (size_t)t * MP * D_IN + rem;
  f16x4 v16 = {(_Float16)0.f, (_Float16)0.f, (_Float16)0.f, (_Float16)0.f};
  if (rem < N_NODES * D_IN) {
    float4 v = *(const float4*)(xs + (size_t)t * N_NODES * D_IN + rem);
    v16[0] = (_Float16)v.x;
    v16[1] = (_Float16)v.y;
    v16[2] = (_Float16)v.z;
    v16[3] = (_Float16)v.w;
  }
  *(f16x4*)(x16 + o) = v16;
}

__global__ void deg_kernel(const int* __restrict__ col, const float* __restrict__ w,
                           float* __restrict__ deg, int* __restrict__ counts) {
  int e = blockIdx.x * blockDim.x + threadIdx.x;
  if (e >= E_EDGES) return;
  int c = col[e];
  atomicAdd(&deg[c], w[e]);
  atomicAdd(&counts[c], 1);
}

__global__ void dinv_kernel(float* __restrict__ deg_dinv, float* __restrict__ selfw) {
  int n = blockIdx.x * blockDim.x + threadIdx.x;
  if (n >= N_NODES) return;
  float d = deg_dinv[n] + 1.0f;
  float di = 1.0f / sqrtf(d);
  deg_dinv[n] = di;
  selfw[n] = 1.0f / d;
}

__global__ __launch_bounds__(1024) void scan_kernel(const int* __restrict__ counts,
                                                    int* __restrict__ offsets, int n) {
  __shared__ int smem[1024];
  __shared__ int carry_s;
  if (threadIdx.x == 0) carry_s = 0;
  __syncthreads();
  for (int base = 0; base < n; base += 1024) {
    int i = base + threadIdx.x;
    int v = (i < n) ? counts[i] : 0;
    smem[threadIdx.x] = v;
    __syncthreads();
    for (int off = 1; off < 1024; off <<= 1) {
      int t = (threadIdx.x >= off) ? smem[threadIdx.x - off] : 0;
      __syncthreads();
      smem[threadIdx.x] += t;
      __syncthreads();
    }
    if (i < n) offsets[i] = carry_s + smem[threadIdx.x] - v;
    int total = smem[1023];
    __syncthreads();
    if (threadIdx.x == 0) carry_s += total;
    __syncthreads();
  }
  if (threadIdx.x == 0) offsets[n] = carry_s;
}

__global__ void scatter_kernel(const int* __restrict__ row, const int* __restrict__ col,
                               const float* __restrict__ w, const float* __restrict__ dinv,
                               const int* __restrict__ offsets, int* __restrict__ cursor,
                               int* __restrict__ csr_row, float* __restrict__ csr_norm) {
  int e = blockIdx.x * blockDim.x + threadIdx.x;
  if (e >= E_EDGES) return;
  int r = row[e], c = col[e];
  float nrm = dinv[r] * w[e] * dinv[c];
  int pos = offsets[c] + atomicAdd(&cursor[c], 1);
  csr_row[pos] = r;
  csr_norm[pos] = nrm;
}

// ---------------- GCN aggregation (fp16 hW) + relu (+ final lin) -----------
__device__ __forceinline__ void fma8h(float* a, float w, const _Float16* p) {
  f16x4 x = *(const f16x4*)p;
  f16x4 y = *(const f16x4*)(p + 256);
  a[0] = fmaf(w, (float)x[0], a[0]);
  a[1] = fmaf(w, (float)x[1], a[1]);
  a[2] = fmaf(w, (float)x[2], a[2]);
  a[3] = fmaf(w, (float)x[3], a[3]);
  a[4] = fmaf(w, (float)y[0], a[4]);
  a[5] = fmaf(w, (float)y[1], a[5]);
  a[6] = fmaf(w, (float)y[2], a[6]);
  a[7] = fmaf(w, (float)y[3], a[7]);
}

template <bool FINAL>
__global__ __launch_bounds__(256) void agg_kernel(
    const _Float16* __restrict__ hW, const int* __restrict__ csr_row,
    const float* __restrict__ csr_norm, const int* __restrict__ offsets,
    const float* __restrict__ selfw, const float* __restrict__ bias,
    _Float16* __restrict__ dst,
    const float* __restrict__ lw, const float* __restrict__ lb,
    float* __restrict__ out) {
  const int n = (blockIdx.x << 2) | (threadIdx.x >> 6);
  const int lane = threadIdx.x & 63;
  if (n >= N_NODES) return;
  const int c0 = lane << 2;
  const int beg = offsets[n], end = offsets[n + 1];
  float a0[8] = {}, a1[8] = {};
  int j = beg;
  for (; j + 4 <= end; j += 4) {
    int r0 = csr_row[j], r1 = csr_row[j + 1], r2 = csr_row[j + 2], r3 = csr_row[j + 3];
    float w0 = csr_norm[j], w1 = csr_norm[j + 1], w2 = csr_norm[j + 2], w3 = csr_norm[j + 3];
    fma8h(a0, w0, hW + (size_t)r0 * H_DIM + c0);
    fma8h(a1, w1, hW + (size_t)r1 * H_DIM + c0);
    fma8h(a0, w2, hW + (size_t)r2 * H_DIM + c0);
    fma8h(a1, w3, hW + (size_t)r3 * H_DIM + c0);
  }
  for (; j < end; ++j) fma8h(a0, csr_norm[j], hW + (size_t)csr_row[j] * H_DIM + c0);

  const float sw = selfw[n];
  const _Float16* ps = hW + (size_t)n * H_DIM + c0;
  f16x4 sa = *(const f16x4*)ps;
  f16x4 sb = *(const f16x4*)(ps + 256);
  float4 ba = *(const float4*)(bias + c0);
  float4 bb = *(const float4*)(bias + 256 + c0);
  float v[8];
  v[0] = fmaxf(fmaf(sw, (float)sa[0], a0[0] + a1[0]) + ba.x, 0.f);
  v[1] = fmaxf(fmaf(sw, (float)sa[1], a0[1] + a1[1]) + ba.y, 0.f);
  v[2] = fmaxf(fmaf(sw, (float)sa[2], a0[2] + a1[2]) + ba.z, 0.f);
  v[3] = fmaxf(fmaf(sw, (float)sa[3], a0[3] + a1[3]) + ba.w, 0.f);
  v[4] = fmaxf(fmaf(sw, (float)sb[0], a0[4] + a1[4]) + bb.x, 0.f);
  v[5] = fmaxf(fmaf(sw, (float)sb[1], a0[5] + a1[5]) + bb.y, 0.f);
  v[6] = fmaxf(fmaf(sw, (float)sb[2], a0[6] + a1[6]) + bb.z, 0.f);
  v[7] = fmaxf(fmaf(sw, (float)sb[3], a0[7] + a1[7]) + bb.w, 0.f);

  size_t o = (size_t)n * H_DIM + c0;
  f16x4 ga = {(_Float16)v[0], (_Float16)v[1], (_Float16)v[2], (_Float16)v[3]};
  f16x4 gb = {(_Float16)v[4], (_Float16)v[5], (_Float16)v[6], (_Float16)v[7]};
  *(f16x4*)(dst + o) = ga;
  *(f16x4*)(dst + o + 256) = gb;

  if (FINAL) {
    float4 la = *(const float4*)(lw + c0);
    float4 lbv = *(const float4*)(lw + 256 + c0);
    float s = v[0] * la.x + v[1] * la.y + v[2] * la.z + v[3] * la.w +
              v[4] * lbv.x + v[5] * lbv.y + v[6] * lbv.z + v[7] * lbv.w;
#pragma unroll
    for (int off2 = 32; off2 > 0; off2 >>= 1) s += __shfl_down(s, off2, 64);
    if (lane == 0) out[n] = s + lb[0];
  }
}

// ---------------- launch ----------------
extern "C" void kernel_launch(void* const* d_in, const int* in_sizes, int n_in,
                              void* d_out, int out_size, void* d_ws, size_t ws_size,
                              hipStream_t stream) {
  const float* xs = (const float*)d_in[0];
  const int* ei = (const int*)d_in[1];
  const float* ew = (const float*)d_in[2];
  const float* W_ih = (const float*)d_in[3];
  const float* W_hh = (const float*)d_in[4];
  const float* b_ih = (const float*)d_in[5];
  const float* b_hh = (const float*)d_in[6];
  const float* conv_W = (const float*)d_in[7];
  const float* conv_b = (const float*)d_in[8];
  const float* lin_W = (const float*)d_in[9];
  const float* lin_b = (const float*)d_in[10];
  float* out = (float*)d_out;

  const int* row = ei;
  const int* col = ei + E_EDGES;

  char* ws = (char*)d_ws;
  size_t off = 0;
  auto alloc = [&](size_t bytes) -> void* {
    void* p = ws + off;
    off += (bytes + 255) & ~(size_t)255;
    return p;
  };
  _Float16* S16 = (_Float16*)alloc((size_t)MP * H_DIM * 2);   // recurrent state
  _Float16* G16 = (_Float16*)alloc((size_t)MP * H_DIM * 2);   // gate/agg0 out
  _Float16* hW16 = (_Float16*)alloc((size_t)MP * H_DIM * 2);
  _Float16* xs16 = (_Float16*)alloc((size_t)T_STEPS * MP * D_IN * 2);
  _Float16* Wih16 = (_Float16*)alloc((size_t)H3 * D_IN * 2);
  _Float16* Whh16 = (_Float16*)alloc((size_t)H3 * H_DIM * 2);
  _Float16* Wc16 = (_Float16*)alloc((size_t)NUM_CONVS * H_DIM * H_DIM * 2);
  float* bihg = (float*)alloc(H3 * 4);
  float* bhhg = (float*)alloc(H3 * 4);
  float* dinv = (float*)alloc(N_NODES * 4);
  float* selfw = (float*)alloc(N_NODES * 4);
  float* csr_norm = (float*)alloc(E_EDGES * 4);
  int* csr_row = (int*)alloc(E_EDGES * 4);
  int* offsets = (int*)alloc((N_NODES + 1) * 4);
  int* counts = (int*)alloc(N_NODES * 4);
  int* cursor = (int*)alloc(N_NODES * 4);

  hipMemsetAsync(S16, 0, (size_t)MP * H_DIM * 2, stream);
  hipMemsetAsync(G16, 0, (size_t)MP * H_DIM * 2, stream);
  hipMemsetAsync(hW16, 0, (size_t)MP * H_DIM * 2, stream);
  hipMemsetAsync(dinv, 0, N_NODES * 4, stream);
  hipMemsetAsync(counts, 0, N_NODES * 4, stream);
  hipMemsetAsync(cursor, 0, N_NODES * 4, stream);

  // one-time preprocessing
  deg_kernel<<<(E_EDGES + 255) / 256, 256, 0, stream>>>(col, ew, dinv, counts);
  dinv_kernel<<<(N_NODES + 255) / 256, 256, 0, stream>>>(dinv, selfw);
  scan_kernel<<<1, 1024, 0, stream>>>(counts, offsets, N_NODES);
  scatter_kernel<<<(E_EDGES + 255) / 256, 256, 0, stream>>>(row, col, ew, dinv, offsets,
                                                            cursor, csr_row, csr_norm);
  split_grouped16<<<(H3 * D_IN + 255) / 256, 256, 0, stream>>>(W_ih, Wih16, D_IN);
  split_grouped16<<<(H3 * H_DIM + 255) / 256, 256, 0, stream>>>(W_hh, Whh16, H_DIM);
  bias_grouped<<<(H3 + 255) / 256, 256, 0, stream>>>(b_ih, b_hh, bihg, bhhg);
  split_convw<<<(NUM_CONVS * H_DIM * H_DIM + 255) / 256, 256, 0, stream>>>(conv_W, Wc16);
  split_xs16<<<(T_STEPS * MP * D_IN / 4 + 255) / 256, 256, 0, stream>>>(xs, xs16);

  dim3 blk(256);
  dim3 g_gru(16, MP / 128);       // 2 jb per block x 79 row-blocks
  dim3 g_conv(H_DIM / 128, MP / 64);  // 4 x 158 = 632 blocks
  int g_agg = (N_NODES + 3) / 4;

  for (int t = 0; t < T_STEPS; ++t) {
    // fused: gi + gh GEMMs + GRU gate -> G16 (fp16)
    gru_fused<<<g_gru, blk, 0, stream>>>(
        xs16 + (size_t)t * MP * D_IN, S16, Wih16, Whh16, bihg, bhhg, G16);
    // conv0: hW16 = G16 @ Wc0 ; agg0 -> G16
    gemm_conv<<<g_conv, blk, 0, stream>>>((const u16*)G16, (const u16*)Wc16, hW16,
                                          N_NODES, H_DIM, H_DIM);
    agg_kernel<false><<<g_agg, 256, 0, stream>>>(
        hW16, csr_row, csr_norm, offsets, selfw, conv_b, G16,
        nullptr, nullptr, nullptr);
    // conv1: hW16 = G16 @ Wc1 ; agg1(final) -> S16 state + fused linear
    gemm_conv<<<g_conv, blk, 0, stream>>>(
        (const u16*)G16, (const u16*)(Wc16 + (size_t)H_DIM * H_DIM), hW16,
        N_NODES, H_DIM, H_DIM);
    agg_kernel<true><<<g_agg, 256, 0, stream>>>(
        hW16, csr_row, csr_norm, offsets, selfw, conv_b + H_DIM, S16,
        lin_W, lin_b, out + (size_t)t * N_NODES);
  }
}